// Round 13
// baseline (429.397 us; speedup 1.0000x reference)
//
#include <hip/hip_runtime.h>
#include <hip/hip_bf16.h>
#include <cstdint>

// SpatialAttentionModule: x[4,256,64,64] fp32; q=Wq x, k=Wk x, v=Wv x (1x1 conv);
// energy = q^T k per batch (N=4096), softmax over j, out = gamma*(v@attn^T) + x.
//
// Round-12 (resubmit; R12 bench was a broker timeout, no data): occupancy x2
// via single-buffered K/V. R11 post-mortem: the 32q/16j-quarter rewrite
// REGRESSED k_attn 140->178us (16x16x16 PV costs the same pipe passes as
// 16x16x32 -> 2x PV pipe time; MfmaUtil up, time up), and halving LDS traffic
// bought nothing -> kernel is NOT LDS-BW-bound; it is latency-bound at
// 2 waves/SIMD (R6: 1->2 waves/SIMD gave 1.27x).
// This round: k_attn reverted to the measured-best R6 structure (139.9us,
// 16q-wave x 32key j-half, PV 16x16x32, P via LDS), with ONE change:
// single K/V buffer (no dbuf) -> LDS 75776B -> 2 blocks/CU = 4 waves/SIMD.
// Lost intra-block prefetch is replaced by cross-block TLP (independent
// blocks overlap DMA-drain stalls with compute). Per tile: compute ->
// barrier -> DMA -> barrier. K/V reads hit L2/L3 (~300cy), hidden by the
// co-resident block. k_cast_w / k_qkv byte-identical to R8.
// MFMA layouts (HW-verified, learn_hip m89/m91, dtype-independent):
//   A[m=lane&15][k=quad*8+j], B[k=quad*8+j][n=lane&15], C/D: col=lane&15, row=quad*4+reg.

#define C_DIM 256
#define N_DIM 4096
#define B_DIM 4

typedef _Float16 f16;
typedef f16 f16x8 __attribute__((ext_vector_type(8)));
typedef f16 f16x4 __attribute__((ext_vector_type(4)));
typedef float f32x4 __attribute__((ext_vector_type(4)));

__device__ __forceinline__ void dma16(const f16* g, f16* l) {
  __builtin_amdgcn_global_load_lds(
      (const __attribute__((address_space(1))) unsigned int*)g,
      (__attribute__((address_space(3))) unsigned int*)l, 16, 0, 0);
}

// ---------------- prep: cast 3 weight matrices -> fp16 [3*256][256] ----------------
__global__ __launch_bounds__(256) void k_cast_w(const float* __restrict__ Wq,
                                                const float* __restrict__ Wk,
                                                const float* __restrict__ Wv,
                                                f16* __restrict__ Wh) {
  int i = blockIdx.x * 256 + threadIdx.x;          // 0 .. 3*65536-1
  int sel = i >> 16, j = i & 65535;
  const float* s = (sel == 0) ? Wq : (sel == 1) ? Wk : Wv;
  Wh[i] = (f16)s[j];
}

// ---------------- fused QKV projection (byte-identical to R8) ----------------
__global__ __launch_bounds__(512) void k_qkv(const float* __restrict__ x,
                                             const f16* __restrict__ Wh,
                                             const float* __restrict__ bq,
                                             const float* __restrict__ bk,
                                             const float* __restrict__ bv,
                                             f16* __restrict__ Qh,
                                             f16* __restrict__ Kh,
                                             f16* __restrict__ Vh) {
  __shared__ __align__(16) f16 xt[64 * 256];   // 32 KiB
  const int b = blockIdx.y, n0 = blockIdx.x * 64;
  const int tid = threadIdx.x;
  const int w = tid >> 6, lane = tid & 63;
  const int quad = lane >> 4, li = lane & 15;
  const int gt = w & 3, role = w >> 2;

  // ---- stage x tile (fp32 -> f16, swizzled) ----
  {
    const float* xb = x + (size_t)b * C_DIM * N_DIM + n0;
#pragma unroll
    for (int cg = 0; cg < 4; cg++) {
      f16x8 v;
#pragma unroll
      for (int j = 0; j < 8; j++) {
        int c = w * 32 + cg * 8 + j;
        v[j] = (f16)xb[(size_t)c * N_DIM + lane];
      }
      int chunk = w * 4 + cg;
      int slot = chunk ^ (lane & 7);
      *(f16x8*)(&xt[lane * 256 + slot * 8]) = v;
    }
  }
  __syncthreads();

  // ---- x fragments (shared by A- and B-roles) ----
  int xsl[8];
#pragma unroll
  for (int kf = 0; kf < 8; kf++) xsl[kf] = ((kf * 4 + quad) ^ (li & 7)) << 3;
  f16x8 xf[8];
  {
    const f16* xrow = xt + (gt * 16 + li) * 256;
#pragma unroll
    for (int kf = 0; kf < 8; kf++) xf[kf] = *(const f16x8*)(xrow + xsl[kf]);
  }

  // ---- Q or K: out[g][o], D rows = o ----
  {
    const f16* W = Wh + (size_t)role * 65536;
    const float* bias = role ? bk : bq;
    f16* out = role ? Kh : Qh;
    const size_t grow = (size_t)(b * N_DIM + n0 + gt * 16 + li) * C_DIM;
    for (int ot = 0; ot < 16; ot++) {
      f32x4 acc = {0.f, 0.f, 0.f, 0.f};
      const f16* wrow = W + (size_t)(ot * 16 + li) * C_DIM + quad * 8;
#pragma unroll
      for (int kf = 0; kf < 8; kf++) {
        f16x8 wf = *(const f16x8*)(wrow + kf * 32);
        acc = __builtin_amdgcn_mfma_f32_16x16x32_f16(wf, xf[kf], acc, 0, 0, 0);
      }
      const int o0 = ot * 16 + quad * 4;
      f16x4 st = {(f16)(acc[0] + bias[o0]), (f16)(acc[1] + bias[o0 + 1]),
                  (f16)(acc[2] + bias[o0 + 2]), (f16)(acc[3] + bias[o0 + 3])};
      *(f16x4*)(out + grow + o0) = st;
    }
  }

  // ---- V half: out[o][j], D rows = j ----
  {
    const f16* W = Wh + (size_t)2 * 65536;
#pragma unroll
    for (int ot8 = 0; ot8 < 8; ot8++) {
      const int ot = role * 8 + ot8;
      f32x4 acc = {0.f, 0.f, 0.f, 0.f};
      const f16* wrow = W + (size_t)(ot * 16 + li) * C_DIM + quad * 8;
#pragma unroll
      for (int kf = 0; kf < 8; kf++) {
        f16x8 wf = *(const f16x8*)(wrow + kf * 32);
        acc = __builtin_amdgcn_mfma_f32_16x16x32_f16(xf[kf], wf, acc, 0, 0, 0);
      }
      const float bb = bv[ot * 16 + li];
      f16x4 st = {(f16)(acc[0] + bb), (f16)(acc[1] + bb),
                  (f16)(acc[2] + bb), (f16)(acc[3] + bb)};
      *(f16x4*)(Vh + (size_t)(b * C_DIM + ot * 16 + li) * N_DIM +
                n0 + gt * 16 + quad * 4) = st;
    }
  }
}

// ---------------- fused attention (R6 structure, single-buffered K/V) ----------------
// grid (64,4): 64-query block, batch. 8 waves: wq=w&3 (16 query cols each),
// wj=w>>2 (j-half of each 64-key tile). Pair (w, w+4) merges at the end.
// JT=64 keys/tile, NT=64 tiles. DMA staging (global_load_lds, 16B), SINGLE
// buffer: per tile {compute -> barrier -> DMA -> barrier}; cross-block TLP
// (2 blocks/CU) hides the DMA drain.
// LDS layouts (f16 units), linear rows + XOR chunk swizzle (chunk = 8 f16 = 16B):
//   K: [64 rows][256], row r: 16B slot s holds global chunk s^(r&7).
//   V: [256 rows][64], row c: slot s holds chunk s^(c&7).
//   P (per wave): [16 i][32 j], row stride 40 f16 (80B, conflict-free).
// Merge scratch (after loop, reuses K/V region as f32):
//   per upper wave u: 16 cols x 260 f32; m/l at f32 offset 16640.
#define JT 64
#define NT (N_DIM / JT)
#define K_OFF 0
#define V_OFF 16384
#define P_OFF 32768
#define PSTR 40
#define SMEM_F16 37888        // 75776 B -> 2 blocks/CU (4 waves/SIMD)
#define MRG_WSTR 4160         // f32 per upper wave (16 cols * 260)
#define MRG_CSTR 260          // f32 col stride
#define ML_OFF   16640        // 4*4160  (16768 f32 = 67072 B <= 75776 B)

__global__ __launch_bounds__(512, 4) void k_attn(const f16* __restrict__ Qh,
                                                 const f16* __restrict__ Kh,
                                                 const f16* __restrict__ Vh,
                                                 const float* __restrict__ x,
                                                 const float* __restrict__ gamma_p,
                                                 float* __restrict__ out) {
  __shared__ __align__(16) f16 smem[SMEM_F16];
  const int b = blockIdx.y;
  const int tid = threadIdx.x;
  const int w = tid >> 6, lane = tid & 63;
  const int wq = w & 3, wj = w >> 2;
  const int quad = lane >> 4, li = lane & 15;
  const int lw = li & 7;
  const int ibase = blockIdx.x * 64 + wq * 16;

  // loop-invariant swizzled slot offsets (f16 units), static-indexed
  int ksl[8];
#pragma unroll
  for (int kf = 0; kf < 8; kf++) ksl[kf] = ((kf * 4 + quad) ^ lw) << 3;
  const int vsl = ((wj * 4 + quad) ^ lw) << 3;   // V j-chunk for this wave's half

  // Q fragments (B-operand: n = query col, k = channel)
  f16x8 qf[8];
  {
    const f16* qrow = Qh + (size_t)(b * N_DIM + ibase + li) * C_DIM + quad * 8;
#pragma unroll
    for (int kf = 0; kf < 8; kf++) qf[kf] = *(const f16x8*)(qrow + kf * 32);
  }
  const f16* Kb = Kh + (size_t)b * N_DIM * C_DIM;
  const f16* Vb = Vh + (size_t)b * C_DIM * N_DIM;
  f16* Pw = smem + P_OFF + w * 16 * PSTR;

  const float LOG2E = 1.4426950408889634f;
  float m = -3.0e38f, l = 0.0f;
  f32x4 acc[16];
#pragma unroll
  for (int ct = 0; ct < 16; ct++) acc[ct] = (f32x4){0.f, 0.f, 0.f, 0.f};

  // prologue: DMA tile 0 (pre-swizzled global source chunks)
  {
#pragma unroll
    for (int it = 0; it < 4; it++) {
      int p = w * 4 + it;
      int krsw = (2 * it + (lane >> 5)) & 7;     // (2p+(l>>5))&7, since 8w==0 mod 8
      dma16(Kb + (size_t)(2 * p + (lane >> 5)) * C_DIM + (((lane & 31) ^ krsw) * 8),
            smem + K_OFF + p * 512);
      dma16(Vb + (size_t)(p * 8 + (lane >> 3)) * N_DIM + (((lane & 7) ^ (lane >> 3)) * 8),
            smem + V_OFF + p * 512);
    }
  }
  __syncthreads();   // drain DMA -> buffer ready

  for (int t = 0; t < NT; t++) {
    const f16* Kc = smem + K_OFF;
    const f16* Vc = smem + V_OFF;

    // ---- S^T for this wave's j-half: rows j = wj*32 + sub*16 + (quad*4+reg) ----
    f32x4 s[2];
#pragma unroll
    for (int sub = 0; sub < 2; sub++) {
      f32x4 ss = {0.f, 0.f, 0.f, 0.f};
      const f16* krow = Kc + (wj * 32 + sub * 16 + li) * 256;  // row&7 == li&7
#pragma unroll
      for (int kf = 0; kf < 8; kf++) {
        f16x8 kfr = *(const f16x8*)(krow + ksl[kf]);
        ss = __builtin_amdgcn_mfma_f32_16x16x32_f16(kfr, qf[kf], ss, 0, 0, 0);
      }
      s[sub] = ss;
    }

    // ---- online softmax over this j-half (per query col li) ----
    float tm = fmaxf(fmaxf(fmaxf(s[0][0], s[0][1]), fmaxf(s[0][2], s[0][3])),
                     fmaxf(fmaxf(s[1][0], s[1][1]), fmaxf(s[1][2], s[1][3])));
    tm = fmaxf(tm, __shfl_xor(tm, 16));
    tm = fmaxf(tm, __shfl_xor(tm, 32));
    float nm = fmaxf(m, tm);
    float alpha = exp2f((m - nm) * LOG2E);
    m = nm;
    if (__any(alpha < 1.0f)) {      // wave-uniform skip when max unchanged
      l *= alpha;
#pragma unroll
      for (int ct = 0; ct < 16; ct++) {
        acc[ct][0] *= alpha; acc[ct][1] *= alpha;
        acc[ct][2] *= alpha; acc[ct][3] *= alpha;
      }
    }
#pragma unroll
    for (int sub = 0; sub < 2; sub++) {
      float p0 = exp2f((s[sub][0] - m) * LOG2E);
      float p1 = exp2f((s[sub][1] - m) * LOG2E);
      float p2 = exp2f((s[sub][2] - m) * LOG2E);
      float p3 = exp2f((s[sub][3] - m) * LOG2E);
      l += (p0 + p1) + (p2 + p3);
      *(f16x4*)(Pw + li * PSTR + sub * 16 + quad * 4) =
          (f16x4){(f16)p0, (f16)p1, (f16)p2, (f16)p3};
    }

    // ---- PV (half): O^T[c][i] += V[c][j-half] P^T[j-half][i], k = 32 ----
    f16x8 pf = *(const f16x8*)(Pw + li * PSTR + quad * 8);
#pragma unroll
    for (int ct = 0; ct < 16; ct++) {
      const f16* vrow = Vc + (ct * 16 + li) * 64;
      f16x8 v = *(const f16x8*)(vrow + vsl);
      acc[ct] = __builtin_amdgcn_mfma_f32_16x16x32_f16(v, pf, acc[ct], 0, 0, 0);
    }

    __syncthreads();   // all waves done reading this tile's K/V

    // ---- DMA tile t+1 into the (single) buffer, then drain ----
    if (t + 1 < NT) {
      const int jt = (t + 1) * JT;
      const f16* kg = Kb + (size_t)jt * C_DIM;
      const f16* vg = Vb + jt;
#pragma unroll
      for (int it = 0; it < 4; it++) {
        int p = w * 4 + it;
        int krsw = (2 * it + (lane >> 5)) & 7;
        dma16(kg + (size_t)(2 * p + (lane >> 5)) * C_DIM + (((lane & 31) ^ krsw) * 8),
              smem + K_OFF + p * 512);
        dma16(vg + (size_t)(p * 8 + (lane >> 3)) * N_DIM + (((lane & 7) ^ (lane >> 3)) * 8),
              smem + V_OFF + p * 512);
      }
      __syncthreads();   // drain DMA -> buffer ready for next iteration
    }
  }

  // ---- reduce l across quads; merge j-half partials via LDS (K/V region reused) ----
  l += __shfl_xor(l, 16);
  l += __shfl_xor(l, 32);

  float* mrg = (float*)smem;
  if (wj == 1) {
    const int u = wq;
    float* base = mrg + u * MRG_WSTR + li * MRG_CSTR;
#pragma unroll
    for (int ct = 0; ct < 16; ct++)
      *(f32x4*)(base + ct * 16 + quad * 4) = acc[ct];
    if (lane < 16) {
      mrg[ML_OFF + u * 32 + li] = m;
      mrg[ML_OFF + u * 32 + 16 + li] = l;
    }
  }
  __syncthreads();
  if (wj == 0) {
    const int u = wq;
    const float m_b = mrg[ML_OFF + u * 32 + li];
    const float l_b = mrg[ML_OFF + u * 32 + 16 + li];
    const float M = fmaxf(m, m_b);
    const float aa = exp2f((m - M) * LOG2E);
    const float ab = exp2f((m_b - M) * LOG2E);
    const float lm = aa * l + ab * l_b;
    const float scale = gamma_p[0] / lm;
    const float* base = mrg + u * MRG_WSTR + li * MRG_CSTR;

    const float* xb = x + (size_t)b * C_DIM * N_DIM;
    float* ob = out + (size_t)b * C_DIM * N_DIM;
    const int icol = ibase + li;
#pragma unroll
    for (int ct = 0; ct < 16; ct++) {
      f32x4 accb = *(const f32x4*)(base + ct * 16 + quad * 4);
#pragma unroll
      for (int r = 0; r < 4; r++) {
        size_t off = (size_t)(ct * 16 + quad * 4 + r) * N_DIM + icol;
        ob[off] = (acc[ct][r] * aa + accb[r] * ab) * scale + xb[off];
      }
    }
  }
}

extern "C" void kernel_launch(void* const* d_in, const int* in_sizes, int n_in,
                              void* d_out, int out_size, void* d_ws, size_t ws_size,
                              hipStream_t stream) {
  const float* x     = (const float*)d_in[0];
  const float* Wq    = (const float*)d_in[1];
  const float* bq    = (const float*)d_in[2];
  const float* Wk    = (const float*)d_in[3];
  const float* bk    = (const float*)d_in[4];
  const float* Wv    = (const float*)d_in[5];
  const float* bv    = (const float*)d_in[6];
  const float* gamma = (const float*)d_in[7];
  float* out = (float*)d_out;

  // workspace: Qh 8MB | Kh 8MB | Vh 8MB | Wh 384KB  (~24.4 MB)
  char* ws = (char*)d_ws;
  f16* Qh = (f16*)(ws);
  f16* Kh = (f16*)(ws + (size_t)8  * 1024 * 1024);
  f16* Vh = (f16*)(ws + (size_t)16 * 1024 * 1024);
  f16* Wh = (f16*)(ws + (size_t)24 * 1024 * 1024);

  k_cast_w<<<dim3(768), 256, 0, stream>>>(Wq, Wk, Wv, Wh);
  k_qkv<<<dim3(64, 4), 512, 0, stream>>>(x, Wh, bq, bk, bv, Qh, Kh, Vh);
  k_attn<<<dim3(64, 4), 512, 0, stream>>>(Qh, Kh, Vh, x, gamma, out);
}

// Round 14
// 281.881 us; speedup vs baseline: 1.5233x; 1.5233x over previous
//
#include <hip/hip_runtime.h>
#include <hip/hip_bf16.h>
#include <cstdint>

// SpatialAttentionModule: x[4,256,64,64] fp32; q=Wq x, k=Wk x, v=Wv x (1x1 conv);
// energy = q^T k per batch (N=4096), softmax over j, out = gamma*(v@attn^T) + x.
//
// Round-14: retest of single-buffered K/V occupancy theory WITHOUT the R13
// spill confound. R13 post-mortem: __launch_bounds__(512,4) capped VGPR at 64
// (needed ~92) -> acc[] spilled to scratch: WRITE_SIZE 16->128MB, FETCH
// 78->158MB, k_attn 140->323us. The occupancy experiment never ran clean.
// This round: identical single-buffer kernel, __launch_bounds__(512,2)
// (VGPR cap 128 >= 92 -> no spill). LDS 75776B x2 = 151.5KB <= 160KB and
// 92 VGPR x 4 waves/SIMD = 368 <= 512 -> 2 blocks/CU feasible.
// Decision rule: Occ~43 but time >=140 -> serialization = TLP gain, revert to
// R6 dbuf for good; Occ stays ~22 -> 2 blocks didn't co-reside, same revert.
// k_cast_w / k_qkv byte-identical to R8.
// MFMA layouts (HW-verified, learn_hip m89/m91, dtype-independent):
//   A[m=lane&15][k=quad*8+j], B[k=quad*8+j][n=lane&15], C/D: col=lane&15, row=quad*4+reg.

#define C_DIM 256
#define N_DIM 4096
#define B_DIM 4

typedef _Float16 f16;
typedef f16 f16x8 __attribute__((ext_vector_type(8)));
typedef f16 f16x4 __attribute__((ext_vector_type(4)));
typedef float f32x4 __attribute__((ext_vector_type(4)));

__device__ __forceinline__ void dma16(const f16* g, f16* l) {
  __builtin_amdgcn_global_load_lds(
      (const __attribute__((address_space(1))) unsigned int*)g,
      (__attribute__((address_space(3))) unsigned int*)l, 16, 0, 0);
}

// ---------------- prep: cast 3 weight matrices -> fp16 [3*256][256] ----------------
__global__ __launch_bounds__(256) void k_cast_w(const float* __restrict__ Wq,
                                                const float* __restrict__ Wk,
                                                const float* __restrict__ Wv,
                                                f16* __restrict__ Wh) {
  int i = blockIdx.x * 256 + threadIdx.x;          // 0 .. 3*65536-1
  int sel = i >> 16, j = i & 65535;
  const float* s = (sel == 0) ? Wq : (sel == 1) ? Wk : Wv;
  Wh[i] = (f16)s[j];
}

// ---------------- fused QKV projection (byte-identical to R8) ----------------
__global__ __launch_bounds__(512) void k_qkv(const float* __restrict__ x,
                                             const f16* __restrict__ Wh,
                                             const float* __restrict__ bq,
                                             const float* __restrict__ bk,
                                             const float* __restrict__ bv,
                                             f16* __restrict__ Qh,
                                             f16* __restrict__ Kh,
                                             f16* __restrict__ Vh) {
  __shared__ __align__(16) f16 xt[64 * 256];   // 32 KiB
  const int b = blockIdx.y, n0 = blockIdx.x * 64;
  const int tid = threadIdx.x;
  const int w = tid >> 6, lane = tid & 63;
  const int quad = lane >> 4, li = lane & 15;
  const int gt = w & 3, role = w >> 2;

  // ---- stage x tile (fp32 -> f16, swizzled) ----
  {
    const float* xb = x + (size_t)b * C_DIM * N_DIM + n0;
#pragma unroll
    for (int cg = 0; cg < 4; cg++) {
      f16x8 v;
#pragma unroll
      for (int j = 0; j < 8; j++) {
        int c = w * 32 + cg * 8 + j;
        v[j] = (f16)xb[(size_t)c * N_DIM + lane];
      }
      int chunk = w * 4 + cg;
      int slot = chunk ^ (lane & 7);
      *(f16x8*)(&xt[lane * 256 + slot * 8]) = v;
    }
  }
  __syncthreads();

  // ---- x fragments (shared by A- and B-roles) ----
  int xsl[8];
#pragma unroll
  for (int kf = 0; kf < 8; kf++) xsl[kf] = ((kf * 4 + quad) ^ (li & 7)) << 3;
  f16x8 xf[8];
  {
    const f16* xrow = xt + (gt * 16 + li) * 256;
#pragma unroll
    for (int kf = 0; kf < 8; kf++) xf[kf] = *(const f16x8*)(xrow + xsl[kf]);
  }

  // ---- Q or K: out[g][o], D rows = o ----
  {
    const f16* W = Wh + (size_t)role * 65536;
    const float* bias = role ? bk : bq;
    f16* out = role ? Kh : Qh;
    const size_t grow = (size_t)(b * N_DIM + n0 + gt * 16 + li) * C_DIM;
    for (int ot = 0; ot < 16; ot++) {
      f32x4 acc = {0.f, 0.f, 0.f, 0.f};
      const f16* wrow = W + (size_t)(ot * 16 + li) * C_DIM + quad * 8;
#pragma unroll
      for (int kf = 0; kf < 8; kf++) {
        f16x8 wf = *(const f16x8*)(wrow + kf * 32);
        acc = __builtin_amdgcn_mfma_f32_16x16x32_f16(wf, xf[kf], acc, 0, 0, 0);
      }
      const int o0 = ot * 16 + quad * 4;
      f16x4 st = {(f16)(acc[0] + bias[o0]), (f16)(acc[1] + bias[o0 + 1]),
                  (f16)(acc[2] + bias[o0 + 2]), (f16)(acc[3] + bias[o0 + 3])};
      *(f16x4*)(out + grow + o0) = st;
    }
  }

  // ---- V half: out[o][j], D rows = j ----
  {
    const f16* W = Wh + (size_t)2 * 65536;
#pragma unroll
    for (int ot8 = 0; ot8 < 8; ot8++) {
      const int ot = role * 8 + ot8;
      f32x4 acc = {0.f, 0.f, 0.f, 0.f};
      const f16* wrow = W + (size_t)(ot * 16 + li) * C_DIM + quad * 8;
#pragma unroll
      for (int kf = 0; kf < 8; kf++) {
        f16x8 wf = *(const f16x8*)(wrow + kf * 32);
        acc = __builtin_amdgcn_mfma_f32_16x16x32_f16(xf[kf], wf, acc, 0, 0, 0);
      }
      const float bb = bv[ot * 16 + li];
      f16x4 st = {(f16)(acc[0] + bb), (f16)(acc[1] + bb),
                  (f16)(acc[2] + bb), (f16)(acc[3] + bb)};
      *(f16x4*)(Vh + (size_t)(b * C_DIM + ot * 16 + li) * N_DIM +
                n0 + gt * 16 + quad * 4) = st;
    }
  }
}

// ---------------- fused attention (R6 structure, single-buffered K/V) ----------------
// grid (64,4): 64-query block, batch. 8 waves: wq=w&3 (16 query cols each),
// wj=w>>2 (j-half of each 64-key tile). Pair (w, w+4) merges at the end.
// JT=64 keys/tile, NT=64 tiles. DMA staging (global_load_lds, 16B), SINGLE
// buffer: per tile {compute -> barrier -> DMA -> barrier}; cross-block TLP
// (2 blocks/CU) hides the DMA drain.
// LDS layouts (f16 units), linear rows + XOR chunk swizzle (chunk = 8 f16 = 16B):
//   K: [64 rows][256], row r: 16B slot s holds global chunk s^(r&7).
//   V: [256 rows][64], row c: slot s holds chunk s^(c&7).
//   P (per wave): [16 i][32 j], row stride 40 f16 (80B, conflict-free).
// Merge scratch (after loop, reuses K/V region as f32):
//   per upper wave u: 16 cols x 260 f32; m/l at f32 offset 16640.
#define JT 64
#define NT (N_DIM / JT)
#define K_OFF 0
#define V_OFF 16384
#define P_OFF 32768
#define PSTR 40
#define SMEM_F16 37888        // 75776 B -> 2 blocks/CU (4 waves/SIMD)
#define MRG_WSTR 4160         // f32 per upper wave (16 cols * 260)
#define MRG_CSTR 260          // f32 col stride
#define ML_OFF   16640        // 4*4160  (16768 f32 = 67072 B <= 75776 B)

__global__ __launch_bounds__(512, 2) void k_attn(const f16* __restrict__ Qh,
                                                 const f16* __restrict__ Kh,
                                                 const f16* __restrict__ Vh,
                                                 const float* __restrict__ x,
                                                 const float* __restrict__ gamma_p,
                                                 float* __restrict__ out) {
  __shared__ __align__(16) f16 smem[SMEM_F16];
  const int b = blockIdx.y;
  const int tid = threadIdx.x;
  const int w = tid >> 6, lane = tid & 63;
  const int wq = w & 3, wj = w >> 2;
  const int quad = lane >> 4, li = lane & 15;
  const int lw = li & 7;
  const int ibase = blockIdx.x * 64 + wq * 16;

  // loop-invariant swizzled slot offsets (f16 units), static-indexed
  int ksl[8];
#pragma unroll
  for (int kf = 0; kf < 8; kf++) ksl[kf] = ((kf * 4 + quad) ^ lw) << 3;
  const int vsl = ((wj * 4 + quad) ^ lw) << 3;   // V j-chunk for this wave's half

  // Q fragments (B-operand: n = query col, k = channel)
  f16x8 qf[8];
  {
    const f16* qrow = Qh + (size_t)(b * N_DIM + ibase + li) * C_DIM + quad * 8;
#pragma unroll
    for (int kf = 0; kf < 8; kf++) qf[kf] = *(const f16x8*)(qrow + kf * 32);
  }
  const f16* Kb = Kh + (size_t)b * N_DIM * C_DIM;
  const f16* Vb = Vh + (size_t)b * C_DIM * N_DIM;
  f16* Pw = smem + P_OFF + w * 16 * PSTR;

  const float LOG2E = 1.4426950408889634f;
  float m = -3.0e38f, l = 0.0f;
  f32x4 acc[16];
#pragma unroll
  for (int ct = 0; ct < 16; ct++) acc[ct] = (f32x4){0.f, 0.f, 0.f, 0.f};

  // prologue: DMA tile 0 (pre-swizzled global source chunks)
  {
#pragma unroll
    for (int it = 0; it < 4; it++) {
      int p = w * 4 + it;
      int krsw = (2 * it + (lane >> 5)) & 7;     // (2p+(l>>5))&7, since 8w==0 mod 8
      dma16(Kb + (size_t)(2 * p + (lane >> 5)) * C_DIM + (((lane & 31) ^ krsw) * 8),
            smem + K_OFF + p * 512);
      dma16(Vb + (size_t)(p * 8 + (lane >> 3)) * N_DIM + (((lane & 7) ^ (lane >> 3)) * 8),
            smem + V_OFF + p * 512);
    }
  }
  __syncthreads();   // drain DMA -> buffer ready

  for (int t = 0; t < NT; t++) {
    const f16* Kc = smem + K_OFF;
    const f16* Vc = smem + V_OFF;

    // ---- S^T for this wave's j-half: rows j = wj*32 + sub*16 + (quad*4+reg) ----
    f32x4 s[2];
#pragma unroll
    for (int sub = 0; sub < 2; sub++) {
      f32x4 ss = {0.f, 0.f, 0.f, 0.f};
      const f16* krow = Kc + (wj * 32 + sub * 16 + li) * 256;  // row&7 == li&7
#pragma unroll
      for (int kf = 0; kf < 8; kf++) {
        f16x8 kfr = *(const f16x8*)(krow + ksl[kf]);
        ss = __builtin_amdgcn_mfma_f32_16x16x32_f16(kfr, qf[kf], ss, 0, 0, 0);
      }
      s[sub] = ss;
    }

    // ---- online softmax over this j-half (per query col li) ----
    float tm = fmaxf(fmaxf(fmaxf(s[0][0], s[0][1]), fmaxf(s[0][2], s[0][3])),
                     fmaxf(fmaxf(s[1][0], s[1][1]), fmaxf(s[1][2], s[1][3])));
    tm = fmaxf(tm, __shfl_xor(tm, 16));
    tm = fmaxf(tm, __shfl_xor(tm, 32));
    float nm = fmaxf(m, tm);
    float alpha = exp2f((m - nm) * LOG2E);
    m = nm;
    if (__any(alpha < 1.0f)) {      // wave-uniform skip when max unchanged
      l *= alpha;
#pragma unroll
      for (int ct = 0; ct < 16; ct++) {
        acc[ct][0] *= alpha; acc[ct][1] *= alpha;
        acc[ct][2] *= alpha; acc[ct][3] *= alpha;
      }
    }
#pragma unroll
    for (int sub = 0; sub < 2; sub++) {
      float p0 = exp2f((s[sub][0] - m) * LOG2E);
      float p1 = exp2f((s[sub][1] - m) * LOG2E);
      float p2 = exp2f((s[sub][2] - m) * LOG2E);
      float p3 = exp2f((s[sub][3] - m) * LOG2E);
      l += (p0 + p1) + (p2 + p3);
      *(f16x4*)(Pw + li * PSTR + sub * 16 + quad * 4) =
          (f16x4){(f16)p0, (f16)p1, (f16)p2, (f16)p3};
    }

    // ---- PV (half): O^T[c][i] += V[c][j-half] P^T[j-half][i], k = 32 ----
    f16x8 pf = *(const f16x8*)(Pw + li * PSTR + quad * 8);
#pragma unroll
    for (int ct = 0; ct < 16; ct++) {
      const f16* vrow = Vc + (ct * 16 + li) * 64;
      f16x8 v = *(const f16x8*)(vrow + vsl);
      acc[ct] = __builtin_amdgcn_mfma_f32_16x16x32_f16(v, pf, acc[ct], 0, 0, 0);
    }

    __syncthreads();   // all waves done reading this tile's K/V

    // ---- DMA tile t+1 into the (single) buffer, then drain ----
    if (t + 1 < NT) {
      const int jt = (t + 1) * JT;
      const f16* kg = Kb + (size_t)jt * C_DIM;
      const f16* vg = Vb + jt;
#pragma unroll
      for (int it = 0; it < 4; it++) {
        int p = w * 4 + it;
        int krsw = (2 * it + (lane >> 5)) & 7;
        dma16(kg + (size_t)(2 * p + (lane >> 5)) * C_DIM + (((lane & 31) ^ krsw) * 8),
              smem + K_OFF + p * 512);
        dma16(vg + (size_t)(p * 8 + (lane >> 3)) * N_DIM + (((lane & 7) ^ (lane >> 3)) * 8),
              smem + V_OFF + p * 512);
      }
      __syncthreads();   // drain DMA -> buffer ready for next iteration
    }
  }

  // ---- reduce l across quads; merge j-half partials via LDS (K/V region reused) ----
  l += __shfl_xor(l, 16);
  l += __shfl_xor(l, 32);

  float* mrg = (float*)smem;
  if (wj == 1) {
    const int u = wq;
    float* base = mrg + u * MRG_WSTR + li * MRG_CSTR;
#pragma unroll
    for (int ct = 0; ct < 16; ct++)
      *(f32x4*)(base + ct * 16 + quad * 4) = acc[ct];
    if (lane < 16) {
      mrg[ML_OFF + u * 32 + li] = m;
      mrg[ML_OFF + u * 32 + 16 + li] = l;
    }
  }
  __syncthreads();
  if (wj == 0) {
    const int u = wq;
    const float m_b = mrg[ML_OFF + u * 32 + li];
    const float l_b = mrg[ML_OFF + u * 32 + 16 + li];
    const float M = fmaxf(m, m_b);
    const float aa = exp2f((m - M) * LOG2E);
    const float ab = exp2f((m_b - M) * LOG2E);
    const float lm = aa * l + ab * l_b;
    const float scale = gamma_p[0] / lm;
    const float* base = mrg + u * MRG_WSTR + li * MRG_CSTR;

    const float* xb = x + (size_t)b * C_DIM * N_DIM;
    float* ob = out + (size_t)b * C_DIM * N_DIM;
    const int icol = ibase + li;
#pragma unroll
    for (int ct = 0; ct < 16; ct++) {
      f32x4 accb = *(const f32x4*)(base + ct * 16 + quad * 4);
#pragma unroll
      for (int r = 0; r < 4; r++) {
        size_t off = (size_t)(ct * 16 + quad * 4 + r) * N_DIM + icol;
        ob[off] = (acc[ct][r] * aa + accb[r] * ab) * scale + xb[off];
      }
    }
  }
}

extern "C" void kernel_launch(void* const* d_in, const int* in_sizes, int n_in,
                              void* d_out, int out_size, void* d_ws, size_t ws_size,
                              hipStream_t stream) {
  const float* x     = (const float*)d_in[0];
  const float* Wq    = (const float*)d_in[1];
  const float* bq    = (const float*)d_in[2];
  const float* Wk    = (const float*)d_in[3];
  const float* bk    = (const float*)d_in[4];
  const float* Wv    = (const float*)d_in[5];
  const float* bv    = (const float*)d_in[6];
  const float* gamma = (const float*)d_in[7];
  float* out = (float*)d_out;

  // workspace: Qh 8MB | Kh 8MB | Vh 8MB | Wh 384KB  (~24.4 MB)
  char* ws = (char*)d_ws;
  f16* Qh = (f16*)(ws);
  f16* Kh = (f16*)(ws + (size_t)8  * 1024 * 1024);
  f16* Vh = (f16*)(ws + (size_t)16 * 1024 * 1024);
  f16* Wh = (f16*)(ws + (size_t)24 * 1024 * 1024);

  k_cast_w<<<dim3(768), 256, 0, stream>>>(Wq, Wk, Wv, Wh);
  k_qkv<<<dim3(64, 4), 512, 0, stream>>>(x, Wh, bq, bk, bv, Qh, Kh, Vh);
  k_attn<<<dim3(64, 4), 512, 0, stream>>>(Qh, Kh, Vh, x, gamma, out);
}

// Round 15
// 249.402 us; speedup vs baseline: 1.7217x; 1.1302x over previous
//
#include <hip/hip_runtime.h>
#include <hip/hip_bf16.h>
#include <cstdint>

// SpatialAttentionModule: x[4,256,64,64] fp32; q=Wq x, k=Wk x, v=Wv x (1x1 conv);
// energy = q^T k per batch (N=4096), softmax over j, out = gamma*(v@attn^T) + x.
//
// Round-15: REVERT to the measured-best configuration (R8: 251.0us total,
// k_attn 139.9us). R14 post-mortem: single-buffer retest ran clean (no spill)
// but Occupancy stayed 22% -- grid 64x4=256 blocks = exactly 1 block/CU, so
// 2 blocks/CU can never co-reside regardless of LDS; the exposed DMA drain
// cost a measured +28.6us (1070 cyc/tile). Ladder: 4w 178 -> 8w+dbuf 139.9
// -> all deviations (k16-PV 178, spill 323, single-buf 168) regressed.
// R6 geometry is a verified local optimum; banking it.
// k_attn: 8 waves (4 wq x 2 wj), JT=64, double-buffered DMA staging,
// XOR-chunk-swizzled LDS (conflict-reduced), PV 16x16x32, P via LDS.
// MFMA layouts (HW-verified, learn_hip m89/m91, dtype-independent):
//   A[m=lane&15][k=quad*8+j], B[k=quad*8+j][n=lane&15], C/D: col=lane&15, row=quad*4+reg.

#define C_DIM 256
#define N_DIM 4096
#define B_DIM 4

typedef _Float16 f16;
typedef f16 f16x8 __attribute__((ext_vector_type(8)));
typedef f16 f16x4 __attribute__((ext_vector_type(4)));
typedef float f32x4 __attribute__((ext_vector_type(4)));

__device__ __forceinline__ void dma16(const f16* g, f16* l) {
  __builtin_amdgcn_global_load_lds(
      (const __attribute__((address_space(1))) unsigned int*)g,
      (__attribute__((address_space(3))) unsigned int*)l, 16, 0, 0);
}

// ---------------- prep: cast 3 weight matrices -> fp16 [3*256][256] ----------------
__global__ __launch_bounds__(256) void k_cast_w(const float* __restrict__ Wq,
                                                const float* __restrict__ Wk,
                                                const float* __restrict__ Wv,
                                                f16* __restrict__ Wh) {
  int i = blockIdx.x * 256 + threadIdx.x;          // 0 .. 3*65536-1
  int sel = i >> 16, j = i & 65535;
  const float* s = (sel == 0) ? Wq : (sel == 1) ? Wk : Wv;
  Wh[i] = (f16)s[j];
}

// ---------------- fused QKV projection (byte-identical to R8) ----------------
__global__ __launch_bounds__(512) void k_qkv(const float* __restrict__ x,
                                             const f16* __restrict__ Wh,
                                             const float* __restrict__ bq,
                                             const float* __restrict__ bk,
                                             const float* __restrict__ bv,
                                             f16* __restrict__ Qh,
                                             f16* __restrict__ Kh,
                                             f16* __restrict__ Vh) {
  __shared__ __align__(16) f16 xt[64 * 256];   // 32 KiB
  const int b = blockIdx.y, n0 = blockIdx.x * 64;
  const int tid = threadIdx.x;
  const int w = tid >> 6, lane = tid & 63;
  const int quad = lane >> 4, li = lane & 15;
  const int gt = w & 3, role = w >> 2;

  // ---- stage x tile (fp32 -> f16, swizzled) ----
  {
    const float* xb = x + (size_t)b * C_DIM * N_DIM + n0;
#pragma unroll
    for (int cg = 0; cg < 4; cg++) {
      f16x8 v;
#pragma unroll
      for (int j = 0; j < 8; j++) {
        int c = w * 32 + cg * 8 + j;
        v[j] = (f16)xb[(size_t)c * N_DIM + lane];
      }
      int chunk = w * 4 + cg;
      int slot = chunk ^ (lane & 7);
      *(f16x8*)(&xt[lane * 256 + slot * 8]) = v;
    }
  }
  __syncthreads();

  // ---- x fragments (shared by A- and B-roles) ----
  int xsl[8];
#pragma unroll
  for (int kf = 0; kf < 8; kf++) xsl[kf] = ((kf * 4 + quad) ^ (li & 7)) << 3;
  f16x8 xf[8];
  {
    const f16* xrow = xt + (gt * 16 + li) * 256;
#pragma unroll
    for (int kf = 0; kf < 8; kf++) xf[kf] = *(const f16x8*)(xrow + xsl[kf]);
  }

  // ---- Q or K: out[g][o], D rows = o ----
  {
    const f16* W = Wh + (size_t)role * 65536;
    const float* bias = role ? bk : bq;
    f16* out = role ? Kh : Qh;
    const size_t grow = (size_t)(b * N_DIM + n0 + gt * 16 + li) * C_DIM;
    for (int ot = 0; ot < 16; ot++) {
      f32x4 acc = {0.f, 0.f, 0.f, 0.f};
      const f16* wrow = W + (size_t)(ot * 16 + li) * C_DIM + quad * 8;
#pragma unroll
      for (int kf = 0; kf < 8; kf++) {
        f16x8 wf = *(const f16x8*)(wrow + kf * 32);
        acc = __builtin_amdgcn_mfma_f32_16x16x32_f16(wf, xf[kf], acc, 0, 0, 0);
      }
      const int o0 = ot * 16 + quad * 4;
      f16x4 st = {(f16)(acc[0] + bias[o0]), (f16)(acc[1] + bias[o0 + 1]),
                  (f16)(acc[2] + bias[o0 + 2]), (f16)(acc[3] + bias[o0 + 3])};
      *(f16x4*)(out + grow + o0) = st;
    }
  }

  // ---- V half: out[o][j], D rows = j ----
  {
    const f16* W = Wh + (size_t)2 * 65536;
#pragma unroll
    for (int ot8 = 0; ot8 < 8; ot8++) {
      const int ot = role * 8 + ot8;
      f32x4 acc = {0.f, 0.f, 0.f, 0.f};
      const f16* wrow = W + (size_t)(ot * 16 + li) * C_DIM + quad * 8;
#pragma unroll
      for (int kf = 0; kf < 8; kf++) {
        f16x8 wf = *(const f16x8*)(wrow + kf * 32);
        acc = __builtin_amdgcn_mfma_f32_16x16x32_f16(xf[kf], wf, acc, 0, 0, 0);
      }
      const float bb = bv[ot * 16 + li];
      f16x4 st = {(f16)(acc[0] + bb), (f16)(acc[1] + bb),
                  (f16)(acc[2] + bb), (f16)(acc[3] + bb)};
      *(f16x4*)(Vh + (size_t)(b * C_DIM + ot * 16 + li) * N_DIM +
                n0 + gt * 16 + quad * 4) = st;
    }
  }
}

// ---------------- fused attention (R6 structure, double-buffered K/V) ----------------
// grid (64,4): 64-query block, batch. 8 waves: wq=w&3 (16 query cols each),
// wj=w>>2 (j-half of each 64-key tile). Pair (w, w+4) merges at the end.
// JT=64 keys/tile, NT=64 tiles. DMA staging (global_load_lds, 16B), dbuf.
// LDS layouts (f16 units), linear rows + XOR chunk swizzle (chunk = 8 f16 = 16B):
//   K: [64 rows][256], row r: 16B slot s holds global chunk s^(r&7).
//   V: [256 rows][64], row c: slot s holds chunk s^(c&7).
//   P (per wave): [16 i][32 j], row stride 40 f16 (80B, conflict-free).
// Merge scratch (after loop, reuses K/V region as f32):
//   per upper wave u: 16 cols x 260 f32; m/l at f32 offset 16640.
#define JT 64
#define NT (N_DIM / JT)
#define K0_OFF 0
#define K1_OFF 16384
#define V0_OFF 32768
#define V1_OFF 49152
#define P_OFF  65536
#define PSTR 40
#define SMEM_F16 70656        // 141312 B
#define MRG_WSTR 4160         // f32 per upper wave (16 cols * 260)
#define MRG_CSTR 260          // f32 col stride
#define ML_OFF   16640        // 4*4160

__global__ __launch_bounds__(512, 1) void k_attn(const f16* __restrict__ Qh,
                                                 const f16* __restrict__ Kh,
                                                 const f16* __restrict__ Vh,
                                                 const float* __restrict__ x,
                                                 const float* __restrict__ gamma_p,
                                                 float* __restrict__ out) {
  __shared__ __align__(16) f16 smem[SMEM_F16];
  const int b = blockIdx.y;
  const int tid = threadIdx.x;
  const int w = tid >> 6, lane = tid & 63;
  const int wq = w & 3, wj = w >> 2;
  const int quad = lane >> 4, li = lane & 15;
  const int lw = li & 7;
  const int ibase = blockIdx.x * 64 + wq * 16;

  // loop-invariant swizzled slot offsets (f16 units), static-indexed
  int ksl[8];
#pragma unroll
  for (int kf = 0; kf < 8; kf++) ksl[kf] = ((kf * 4 + quad) ^ lw) << 3;
  const int vsl = ((wj * 4 + quad) ^ lw) << 3;   // V j-chunk for this wave's half

  // Q fragments (B-operand: n = query col, k = channel)
  f16x8 qf[8];
  {
    const f16* qrow = Qh + (size_t)(b * N_DIM + ibase + li) * C_DIM + quad * 8;
#pragma unroll
    for (int kf = 0; kf < 8; kf++) qf[kf] = *(const f16x8*)(qrow + kf * 32);
  }
  const f16* Kb = Kh + (size_t)b * N_DIM * C_DIM;
  const f16* Vb = Vh + (size_t)b * C_DIM * N_DIM;
  f16* Pw = smem + P_OFF + w * 16 * PSTR;

  const float LOG2E = 1.4426950408889634f;
  float m = -3.0e38f, l = 0.0f;
  f32x4 acc[16];
#pragma unroll
  for (int ct = 0; ct < 16; ct++) acc[ct] = (f32x4){0.f, 0.f, 0.f, 0.f};

  // prologue: DMA tile 0 -> buf0 (pre-swizzled global source chunks)
  {
#pragma unroll
    for (int it = 0; it < 4; it++) {
      int p = w * 4 + it;
      int krsw = (2 * it + (lane >> 5)) & 7;     // (2p+(l>>5))&7, since 8w==0 mod 8
      dma16(Kb + (size_t)(2 * p + (lane >> 5)) * C_DIM + (((lane & 31) ^ krsw) * 8),
            smem + K0_OFF + p * 512);
      dma16(Vb + (size_t)(p * 8 + (lane >> 3)) * N_DIM + (((lane & 7) ^ (lane >> 3)) * 8),
            smem + V0_OFF + p * 512);
    }
  }
  __syncthreads();

  for (int t = 0; t < NT; t++) {
    const f16* Kc = smem + ((t & 1) ? K1_OFF : K0_OFF);
    const f16* Vc = smem + ((t & 1) ? V1_OFF : V0_OFF);

    // issue DMA for tile t+1 into the other buffer (drained at the barrier)
    if (t + 1 < NT) {
      f16* Kn = smem + ((t & 1) ? K0_OFF : K1_OFF);
      f16* Vn = smem + ((t & 1) ? V0_OFF : V1_OFF);
      const int jt = (t + 1) * JT;
      const f16* kg = Kb + (size_t)jt * C_DIM;
      const f16* vg = Vb + jt;
#pragma unroll
      for (int it = 0; it < 4; it++) {
        int p = w * 4 + it;
        int krsw = (2 * it + (lane >> 5)) & 7;
        dma16(kg + (size_t)(2 * p + (lane >> 5)) * C_DIM + (((lane & 31) ^ krsw) * 8),
              Kn + p * 512);
        dma16(vg + (size_t)(p * 8 + (lane >> 3)) * N_DIM + (((lane & 7) ^ (lane >> 3)) * 8),
              Vn + p * 512);
      }
    }

    // ---- S^T for this wave's j-half: rows j = wj*32 + sub*16 + (quad*4+reg) ----
    f32x4 s[2];
#pragma unroll
    for (int sub = 0; sub < 2; sub++) {
      f32x4 ss = {0.f, 0.f, 0.f, 0.f};
      const f16* krow = Kc + (wj * 32 + sub * 16 + li) * 256;  // row&7 == li&7
#pragma unroll
      for (int kf = 0; kf < 8; kf++) {
        f16x8 kfr = *(const f16x8*)(krow + ksl[kf]);
        ss = __builtin_amdgcn_mfma_f32_16x16x32_f16(kfr, qf[kf], ss, 0, 0, 0);
      }
      s[sub] = ss;
    }

    // ---- online softmax over this j-half (per query col li) ----
    float tm = fmaxf(fmaxf(fmaxf(s[0][0], s[0][1]), fmaxf(s[0][2], s[0][3])),
                     fmaxf(fmaxf(s[1][0], s[1][1]), fmaxf(s[1][2], s[1][3])));
    tm = fmaxf(tm, __shfl_xor(tm, 16));
    tm = fmaxf(tm, __shfl_xor(tm, 32));
    float nm = fmaxf(m, tm);
    float alpha = exp2f((m - nm) * LOG2E);
    m = nm;
    if (__any(alpha < 1.0f)) {      // wave-uniform skip when max unchanged
      l *= alpha;
#pragma unroll
      for (int ct = 0; ct < 16; ct++) {
        acc[ct][0] *= alpha; acc[ct][1] *= alpha;
        acc[ct][2] *= alpha; acc[ct][3] *= alpha;
      }
    }
#pragma unroll
    for (int sub = 0; sub < 2; sub++) {
      float p0 = exp2f((s[sub][0] - m) * LOG2E);
      float p1 = exp2f((s[sub][1] - m) * LOG2E);
      float p2 = exp2f((s[sub][2] - m) * LOG2E);
      float p3 = exp2f((s[sub][3] - m) * LOG2E);
      l += (p0 + p1) + (p2 + p3);
      *(f16x4*)(Pw + li * PSTR + sub * 16 + quad * 4) =
          (f16x4){(f16)p0, (f16)p1, (f16)p2, (f16)p3};
    }

    // ---- PV (half): O^T[c][i] += V[c][j-half] P^T[j-half][i], k = 32 ----
    f16x8 pf = *(const f16x8*)(Pw + li * PSTR + quad * 8);
#pragma unroll
    for (int ct = 0; ct < 16; ct++) {
      const f16* vrow = Vc + (ct * 16 + li) * 64;
      f16x8 v = *(const f16x8*)(vrow + vsl);
      acc[ct] = __builtin_amdgcn_mfma_f32_16x16x32_f16(v, pf, acc[ct], 0, 0, 0);
    }

    __syncthreads();   // waits readers of current bufs AND drains next-tile DMA
  }

  // ---- reduce l across quads; merge j-half partials via LDS (K/V region reused) ----
  l += __shfl_xor(l, 16);
  l += __shfl_xor(l, 32);

  float* mrg = (float*)smem;
  if (wj == 1) {
    const int u = wq;
    float* base = mrg + u * MRG_WSTR + li * MRG_CSTR;
#pragma unroll
    for (int ct = 0; ct < 16; ct++)
      *(f32x4*)(base + ct * 16 + quad * 4) = acc[ct];
    if (lane < 16) {
      mrg[ML_OFF + u * 32 + li] = m;
      mrg[ML_OFF + u * 32 + 16 + li] = l;
    }
  }
  __syncthreads();
  if (wj == 0) {
    const int u = wq;
    const float m_b = mrg[ML_OFF + u * 32 + li];
    const float l_b = mrg[ML_OFF + u * 32 + 16 + li];
    const float M = fmaxf(m, m_b);
    const float aa = exp2f((m - M) * LOG2E);
    const float ab = exp2f((m_b - M) * LOG2E);
    const float lm = aa * l + ab * l_b;
    const float scale = gamma_p[0] / lm;
    const float* base = mrg + u * MRG_WSTR + li * MRG_CSTR;

    const float* xb = x + (size_t)b * C_DIM * N_DIM;
    float* ob = out + (size_t)b * C_DIM * N_DIM;
    const int icol = ibase + li;
#pragma unroll
    for (int ct = 0; ct < 16; ct++) {
      f32x4 accb = *(const f32x4*)(base + ct * 16 + quad * 4);
#pragma unroll
      for (int r = 0; r < 4; r++) {
        size_t off = (size_t)(ct * 16 + quad * 4 + r) * N_DIM + icol;
        ob[off] = (acc[ct][r] * aa + accb[r] * ab) * scale + xb[off];
      }
    }
  }
}

extern "C" void kernel_launch(void* const* d_in, const int* in_sizes, int n_in,
                              void* d_out, int out_size, void* d_ws, size_t ws_size,
                              hipStream_t stream) {
  const float* x     = (const float*)d_in[0];
  const float* Wq    = (const float*)d_in[1];
  const float* bq    = (const float*)d_in[2];
  const float* Wk    = (const float*)d_in[3];
  const float* bk    = (const float*)d_in[4];
  const float* Wv    = (const float*)d_in[5];
  const float* bv    = (const float*)d_in[6];
  const float* gamma = (const float*)d_in[7];
  float* out = (float*)d_out;

  // workspace: Qh 8MB | Kh 8MB | Vh 8MB | Wh 384KB  (~24.4 MB)
  char* ws = (char*)d_ws;
  f16* Qh = (f16*)(ws);
  f16* Kh = (f16*)(ws + (size_t)8  * 1024 * 1024);
  f16* Vh = (f16*)(ws + (size_t)16 * 1024 * 1024);
  f16* Wh = (f16*)(ws + (size_t)24 * 1024 * 1024);

  k_cast_w<<<dim3(768), 256, 0, stream>>>(Wq, Wk, Wv, Wh);
  k_qkv<<<dim3(64, 4), 512, 0, stream>>>(x, Wh, bq, bk, bv, Qh, Kh, Vh);
  k_attn<<<dim3(64, 4), 512, 0, stream>>>(Qh, Kh, Vh, x, gamma, out);
}

// Round 16
// 247.788 us; speedup vs baseline: 1.7329x; 1.0065x over previous
//
#include <hip/hip_runtime.h>
#include <hip/hip_bf16.h>
#include <cstdint>

// SpatialAttentionModule: x[4,256,64,64] fp32; q=Wq x, k=Wk x, v=Wv x (1x1 conv);
// energy = q^T k per batch (N=4096), softmax over j, out = gamma*(v@attn^T) + x.
//
// Round-16: T13 defer-max on the banked R15 base (249.4us, k_attn 141.2us).
// R15 confirmed the R6/R8 geometry as a verified local optimum (all 4
// structural deviations regressed). Single change: rescale gate
// __any(alpha<1) -> __any(tm - m > 8). Old gate fires on ~55-59/63 tiles
// (any of 16 cols sees a new max, P~16/(t+1)); the 64-VALU acc-rescale sits
// on the per-tile serial chain (latency-bound kernel). THR=8 keeps a stale m
// while growth <= 8: P bounded by e^8~2981 (f16 ok), l <= 4096*e^8 (f32 ok),
// math exact (m/l/acc self-consistent; merge handles any m). Rescales drop
// to ~2-4 total. Guide T13: +5% attn, refcheck'd, data-independent.
// k_cast_w / k_qkv byte-identical to R8.
// MFMA layouts (HW-verified, learn_hip m89/m91, dtype-independent):
//   A[m=lane&15][k=quad*8+j], B[k=quad*8+j][n=lane&15], C/D: col=lane&15, row=quad*4+reg.

#define C_DIM 256
#define N_DIM 4096
#define B_DIM 4

typedef _Float16 f16;
typedef f16 f16x8 __attribute__((ext_vector_type(8)));
typedef f16 f16x4 __attribute__((ext_vector_type(4)));
typedef float f32x4 __attribute__((ext_vector_type(4)));

__device__ __forceinline__ void dma16(const f16* g, f16* l) {
  __builtin_amdgcn_global_load_lds(
      (const __attribute__((address_space(1))) unsigned int*)g,
      (__attribute__((address_space(3))) unsigned int*)l, 16, 0, 0);
}

// ---------------- prep: cast 3 weight matrices -> fp16 [3*256][256] ----------------
__global__ __launch_bounds__(256) void k_cast_w(const float* __restrict__ Wq,
                                                const float* __restrict__ Wk,
                                                const float* __restrict__ Wv,
                                                f16* __restrict__ Wh) {
  int i = blockIdx.x * 256 + threadIdx.x;          // 0 .. 3*65536-1
  int sel = i >> 16, j = i & 65535;
  const float* s = (sel == 0) ? Wq : (sel == 1) ? Wk : Wv;
  Wh[i] = (f16)s[j];
}

// ---------------- fused QKV projection (byte-identical to R8) ----------------
__global__ __launch_bounds__(512) void k_qkv(const float* __restrict__ x,
                                             const f16* __restrict__ Wh,
                                             const float* __restrict__ bq,
                                             const float* __restrict__ bk,
                                             const float* __restrict__ bv,
                                             f16* __restrict__ Qh,
                                             f16* __restrict__ Kh,
                                             f16* __restrict__ Vh) {
  __shared__ __align__(16) f16 xt[64 * 256];   // 32 KiB
  const int b = blockIdx.y, n0 = blockIdx.x * 64;
  const int tid = threadIdx.x;
  const int w = tid >> 6, lane = tid & 63;
  const int quad = lane >> 4, li = lane & 15;
  const int gt = w & 3, role = w >> 2;

  // ---- stage x tile (fp32 -> f16, swizzled) ----
  {
    const float* xb = x + (size_t)b * C_DIM * N_DIM + n0;
#pragma unroll
    for (int cg = 0; cg < 4; cg++) {
      f16x8 v;
#pragma unroll
      for (int j = 0; j < 8; j++) {
        int c = w * 32 + cg * 8 + j;
        v[j] = (f16)xb[(size_t)c * N_DIM + lane];
      }
      int chunk = w * 4 + cg;
      int slot = chunk ^ (lane & 7);
      *(f16x8*)(&xt[lane * 256 + slot * 8]) = v;
    }
  }
  __syncthreads();

  // ---- x fragments (shared by A- and B-roles) ----
  int xsl[8];
#pragma unroll
  for (int kf = 0; kf < 8; kf++) xsl[kf] = ((kf * 4 + quad) ^ (li & 7)) << 3;
  f16x8 xf[8];
  {
    const f16* xrow = xt + (gt * 16 + li) * 256;
#pragma unroll
    for (int kf = 0; kf < 8; kf++) xf[kf] = *(const f16x8*)(xrow + xsl[kf]);
  }

  // ---- Q or K: out[g][o], D rows = o ----
  {
    const f16* W = Wh + (size_t)role * 65536;
    const float* bias = role ? bk : bq;
    f16* out = role ? Kh : Qh;
    const size_t grow = (size_t)(b * N_DIM + n0 + gt * 16 + li) * C_DIM;
    for (int ot = 0; ot < 16; ot++) {
      f32x4 acc = {0.f, 0.f, 0.f, 0.f};
      const f16* wrow = W + (size_t)(ot * 16 + li) * C_DIM + quad * 8;
#pragma unroll
      for (int kf = 0; kf < 8; kf++) {
        f16x8 wf = *(const f16x8*)(wrow + kf * 32);
        acc = __builtin_amdgcn_mfma_f32_16x16x32_f16(wf, xf[kf], acc, 0, 0, 0);
      }
      const int o0 = ot * 16 + quad * 4;
      f16x4 st = {(f16)(acc[0] + bias[o0]), (f16)(acc[1] + bias[o0 + 1]),
                  (f16)(acc[2] + bias[o0 + 2]), (f16)(acc[3] + bias[o0 + 3])};
      *(f16x4*)(out + grow + o0) = st;
    }
  }

  // ---- V half: out[o][j], D rows = j ----
  {
    const f16* W = Wh + (size_t)2 * 65536;
#pragma unroll
    for (int ot8 = 0; ot8 < 8; ot8++) {
      const int ot = role * 8 + ot8;
      f32x4 acc = {0.f, 0.f, 0.f, 0.f};
      const f16* wrow = W + (size_t)(ot * 16 + li) * C_DIM + quad * 8;
#pragma unroll
      for (int kf = 0; kf < 8; kf++) {
        f16x8 wf = *(const f16x8*)(wrow + kf * 32);
        acc = __builtin_amdgcn_mfma_f32_16x16x32_f16(xf[kf], wf, acc, 0, 0, 0);
      }
      const float bb = bv[ot * 16 + li];
      f16x4 st = {(f16)(acc[0] + bb), (f16)(acc[1] + bb),
                  (f16)(acc[2] + bb), (f16)(acc[3] + bb)};
      *(f16x4*)(Vh + (size_t)(b * C_DIM + ot * 16 + li) * N_DIM +
                n0 + gt * 16 + quad * 4) = st;
    }
  }
}

// ---------------- fused attention (R6 structure + T13 defer-max) ----------------
// grid (64,4): 64-query block, batch. 8 waves: wq=w&3 (16 query cols each),
// wj=w>>2 (j-half of each 64-key tile). Pair (w, w+4) merges at the end.
// JT=64 keys/tile, NT=64 tiles. DMA staging (global_load_lds, 16B), dbuf.
// LDS layouts (f16 units), linear rows + XOR chunk swizzle (chunk = 8 f16 = 16B):
//   K: [64 rows][256], row r: 16B slot s holds global chunk s^(r&7).
//   V: [256 rows][64], row c: slot s holds chunk s^(c&7).
//   P (per wave): [16 i][32 j], row stride 40 f16 (80B, conflict-free).
// Merge scratch (after loop, reuses K/V region as f32):
//   per upper wave u: 16 cols x 260 f32; m/l at f32 offset 16640.
#define JT 64
#define NT (N_DIM / JT)
#define K0_OFF 0
#define K1_OFF 16384
#define V0_OFF 32768
#define V1_OFF 49152
#define P_OFF  65536
#define PSTR 40
#define SMEM_F16 70656        // 141312 B
#define MRG_WSTR 4160         // f32 per upper wave (16 cols * 260)
#define MRG_CSTR 260          // f32 col stride
#define ML_OFF   16640        // 4*4160
#define RESCALE_THR 8.0f      // defer-max threshold (P <= e^8 ~ 2981, f16-safe)

__global__ __launch_bounds__(512, 1) void k_attn(const f16* __restrict__ Qh,
                                                 const f16* __restrict__ Kh,
                                                 const f16* __restrict__ Vh,
                                                 const float* __restrict__ x,
                                                 const float* __restrict__ gamma_p,
                                                 float* __restrict__ out) {
  __shared__ __align__(16) f16 smem[SMEM_F16];
  const int b = blockIdx.y;
  const int tid = threadIdx.x;
  const int w = tid >> 6, lane = tid & 63;
  const int wq = w & 3, wj = w >> 2;
  const int quad = lane >> 4, li = lane & 15;
  const int lw = li & 7;
  const int ibase = blockIdx.x * 64 + wq * 16;

  // loop-invariant swizzled slot offsets (f16 units), static-indexed
  int ksl[8];
#pragma unroll
  for (int kf = 0; kf < 8; kf++) ksl[kf] = ((kf * 4 + quad) ^ lw) << 3;
  const int vsl = ((wj * 4 + quad) ^ lw) << 3;   // V j-chunk for this wave's half

  // Q fragments (B-operand: n = query col, k = channel)
  f16x8 qf[8];
  {
    const f16* qrow = Qh + (size_t)(b * N_DIM + ibase + li) * C_DIM + quad * 8;
#pragma unroll
    for (int kf = 0; kf < 8; kf++) qf[kf] = *(const f16x8*)(qrow + kf * 32);
  }
  const f16* Kb = Kh + (size_t)b * N_DIM * C_DIM;
  const f16* Vb = Vh + (size_t)b * C_DIM * N_DIM;
  f16* Pw = smem + P_OFF + w * 16 * PSTR;

  const float LOG2E = 1.4426950408889634f;
  float m = -3.0e38f, l = 0.0f;
  f32x4 acc[16];
#pragma unroll
  for (int ct = 0; ct < 16; ct++) acc[ct] = (f32x4){0.f, 0.f, 0.f, 0.f};

  // prologue: DMA tile 0 -> buf0 (pre-swizzled global source chunks)
  {
#pragma unroll
    for (int it = 0; it < 4; it++) {
      int p = w * 4 + it;
      int krsw = (2 * it + (lane >> 5)) & 7;     // (2p+(l>>5))&7, since 8w==0 mod 8
      dma16(Kb + (size_t)(2 * p + (lane >> 5)) * C_DIM + (((lane & 31) ^ krsw) * 8),
            smem + K0_OFF + p * 512);
      dma16(Vb + (size_t)(p * 8 + (lane >> 3)) * N_DIM + (((lane & 7) ^ (lane >> 3)) * 8),
            smem + V0_OFF + p * 512);
    }
  }
  __syncthreads();

  for (int t = 0; t < NT; t++) {
    const f16* Kc = smem + ((t & 1) ? K1_OFF : K0_OFF);
    const f16* Vc = smem + ((t & 1) ? V1_OFF : V0_OFF);

    // issue DMA for tile t+1 into the other buffer (drained at the barrier)
    if (t + 1 < NT) {
      f16* Kn = smem + ((t & 1) ? K0_OFF : K1_OFF);
      f16* Vn = smem + ((t & 1) ? V0_OFF : V1_OFF);
      const int jt = (t + 1) * JT;
      const f16* kg = Kb + (size_t)jt * C_DIM;
      const f16* vg = Vb + jt;
#pragma unroll
      for (int it = 0; it < 4; it++) {
        int p = w * 4 + it;
        int krsw = (2 * it + (lane >> 5)) & 7;
        dma16(kg + (size_t)(2 * p + (lane >> 5)) * C_DIM + (((lane & 31) ^ krsw) * 8),
              Kn + p * 512);
        dma16(vg + (size_t)(p * 8 + (lane >> 3)) * N_DIM + (((lane & 7) ^ (lane >> 3)) * 8),
              Vn + p * 512);
      }
    }

    // ---- S^T for this wave's j-half: rows j = wj*32 + sub*16 + (quad*4+reg) ----
    f32x4 s[2];
#pragma unroll
    for (int sub = 0; sub < 2; sub++) {
      f32x4 ss = {0.f, 0.f, 0.f, 0.f};
      const f16* krow = Kc + (wj * 32 + sub * 16 + li) * 256;  // row&7 == li&7
#pragma unroll
      for (int kf = 0; kf < 8; kf++) {
        f16x8 kfr = *(const f16x8*)(krow + ksl[kf]);
        ss = __builtin_amdgcn_mfma_f32_16x16x32_f16(kfr, qf[kf], ss, 0, 0, 0);
      }
      s[sub] = ss;
    }

    // ---- online softmax over this j-half (per query col li), defer-max T13 ----
    float tm = fmaxf(fmaxf(fmaxf(s[0][0], s[0][1]), fmaxf(s[0][2], s[0][3])),
                     fmaxf(fmaxf(s[1][0], s[1][1]), fmaxf(s[1][2], s[1][3])));
    tm = fmaxf(tm, __shfl_xor(tm, 16));
    tm = fmaxf(tm, __shfl_xor(tm, 32));
    if (__any(tm - m > RESCALE_THR)) {   // wave-uniform; rare after first tiles
      float nm = fmaxf(m, tm);
      float alpha = exp2f((m - nm) * LOG2E);
      m = nm;
      l *= alpha;
#pragma unroll
      for (int ct = 0; ct < 16; ct++) {
        acc[ct][0] *= alpha; acc[ct][1] *= alpha;
        acc[ct][2] *= alpha; acc[ct][3] *= alpha;
      }
    }
#pragma unroll
    for (int sub = 0; sub < 2; sub++) {
      float p0 = exp2f((s[sub][0] - m) * LOG2E);
      float p1 = exp2f((s[sub][1] - m) * LOG2E);
      float p2 = exp2f((s[sub][2] - m) * LOG2E);
      float p3 = exp2f((s[sub][3] - m) * LOG2E);
      l += (p0 + p1) + (p2 + p3);
      *(f16x4*)(Pw + li * PSTR + sub * 16 + quad * 4) =
          (f16x4){(f16)p0, (f16)p1, (f16)p2, (f16)p3};
    }

    // ---- PV (half): O^T[c][i] += V[c][j-half] P^T[j-half][i], k = 32 ----
    f16x8 pf = *(const f16x8*)(Pw + li * PSTR + quad * 8);
#pragma unroll
    for (int ct = 0; ct < 16; ct++) {
      const f16* vrow = Vc + (ct * 16 + li) * 64;
      f16x8 v = *(const f16x8*)(vrow + vsl);
      acc[ct] = __builtin_amdgcn_mfma_f32_16x16x32_f16(v, pf, acc[ct], 0, 0, 0);
    }

    __syncthreads();   // waits readers of current bufs AND drains next-tile DMA
  }

  // ---- reduce l across quads; merge j-half partials via LDS (K/V region reused) ----
  l += __shfl_xor(l, 16);
  l += __shfl_xor(l, 32);

  float* mrg = (float*)smem;
  if (wj == 1) {
    const int u = wq;
    float* base = mrg + u * MRG_WSTR + li * MRG_CSTR;
#pragma unroll
    for (int ct = 0; ct < 16; ct++)
      *(f32x4*)(base + ct * 16 + quad * 4) = acc[ct];
    if (lane < 16) {
      mrg[ML_OFF + u * 32 + li] = m;
      mrg[ML_OFF + u * 32 + 16 + li] = l;
    }
  }
  __syncthreads();
  if (wj == 0) {
    const int u = wq;
    const float m_b = mrg[ML_OFF + u * 32 + li];
    const float l_b = mrg[ML_OFF + u * 32 + 16 + li];
    const float M = fmaxf(m, m_b);
    const float aa = exp2f((m - M) * LOG2E);
    const float ab = exp2f((m_b - M) * LOG2E);
    const float lm = aa * l + ab * l_b;
    const float scale = gamma_p[0] / lm;
    const float* base = mrg + u * MRG_WSTR + li * MRG_CSTR;

    const float* xb = x + (size_t)b * C_DIM * N_DIM;
    float* ob = out + (size_t)b * C_DIM * N_DIM;
    const int icol = ibase + li;
#pragma unroll
    for (int ct = 0; ct < 16; ct++) {
      f32x4 accb = *(const f32x4*)(base + ct * 16 + quad * 4);
#pragma unroll
      for (int r = 0; r < 4; r++) {
        size_t off = (size_t)(ct * 16 + quad * 4 + r) * N_DIM + icol;
        ob[off] = (acc[ct][r] * aa + accb[r] * ab) * scale + xb[off];
      }
    }
  }
}

extern "C" void kernel_launch(void* const* d_in, const int* in_sizes, int n_in,
                              void* d_out, int out_size, void* d_ws, size_t ws_size,
                              hipStream_t stream) {
  const float* x     = (const float*)d_in[0];
  const float* Wq    = (const float*)d_in[1];
  const float* bq    = (const float*)d_in[2];
  const float* Wk    = (const float*)d_in[3];
  const float* bk    = (const float*)d_in[4];
  const float* Wv    = (const float*)d_in[5];
  const float* bv    = (const float*)d_in[6];
  const float* gamma = (const float*)d_in[7];
  float* out = (float*)d_out;

  // workspace: Qh 8MB | Kh 8MB | Vh 8MB | Wh 384KB  (~24.4 MB)
  char* ws = (char*)d_ws;
  f16* Qh = (f16*)(ws);
  f16* Kh = (f16*)(ws + (size_t)8  * 1024 * 1024);
  f16* Vh = (f16*)(ws + (size_t)16 * 1024 * 1024);
  f16* Wh = (f16*)(ws + (size_t)24 * 1024 * 1024);

  k_cast_w<<<dim3(768), 256, 0, stream>>>(Wq, Wk, Wv, Wh);
  k_qkv<<<dim3(64, 4), 512, 0, stream>>>(x, Wh, bq, bk, bv, Qh, Kh, Vh);
  k_attn<<<dim3(64, 4), 512, 0, stream>>>(Qh, Kh, Vh, x, gamma, out);
}

// Round 17
// 241.174 us; speedup vs baseline: 1.7804x; 1.0274x over previous
//
#include <hip/hip_runtime.h>
#include <hip/hip_bf16.h>
#include <cstdint>

// SpatialAttentionModule: x[4,256,64,64] fp32; q=Wq x, k=Wk x, v=Wv x (1x1 conv);
// energy = q^T k per batch (N=4096), softmax over j, out = gamma*(v@attn^T) + x.
//
// Round-17: shfl-hoist on the R16 base (247.8us, k_attn 136.4us, T13 banked
// at predicted +5us). Single change: the 2 cross-quad __shfl_xor max
// reductions ran EVERY tile but their result (tm) is only consumed when the
// rescale fires (~2-4/64 tiles with THR=8). Gate is exactly computable from
// the per-lane 8-element partial max pm: colmax > m+THR iff some lane's
// pm > m+THR (colmax = max of 4 lanes' pm; __any spans all lanes; m is
// column-uniform since it only updates from post-shfl column-uniform tm
// inside the branch). Hoist shfl pair into the branch -> common path drops
// 2 DS-unit round-trips (~30-60cy each) from the per-tile serial chain.
// Kernel is latency-bound (LDS 52%, VALU 32%, MFMA 21% busy; 2 waves/SIMD,
// grid-capped): serial-chain trims are the remaining lever.
// k_cast_w / k_qkv byte-identical to R8.
// MFMA layouts (HW-verified, learn_hip m89/m91, dtype-independent):
//   A[m=lane&15][k=quad*8+j], B[k=quad*8+j][n=lane&15], C/D: col=lane&15, row=quad*4+reg.

#define C_DIM 256
#define N_DIM 4096
#define B_DIM 4

typedef _Float16 f16;
typedef f16 f16x8 __attribute__((ext_vector_type(8)));
typedef f16 f16x4 __attribute__((ext_vector_type(4)));
typedef float f32x4 __attribute__((ext_vector_type(4)));

__device__ __forceinline__ void dma16(const f16* g, f16* l) {
  __builtin_amdgcn_global_load_lds(
      (const __attribute__((address_space(1))) unsigned int*)g,
      (__attribute__((address_space(3))) unsigned int*)l, 16, 0, 0);
}

// ---------------- prep: cast 3 weight matrices -> fp16 [3*256][256] ----------------
__global__ __launch_bounds__(256) void k_cast_w(const float* __restrict__ Wq,
                                                const float* __restrict__ Wk,
                                                const float* __restrict__ Wv,
                                                f16* __restrict__ Wh) {
  int i = blockIdx.x * 256 + threadIdx.x;          // 0 .. 3*65536-1
  int sel = i >> 16, j = i & 65535;
  const float* s = (sel == 0) ? Wq : (sel == 1) ? Wk : Wv;
  Wh[i] = (f16)s[j];
}

// ---------------- fused QKV projection (byte-identical to R8) ----------------
__global__ __launch_bounds__(512) void k_qkv(const float* __restrict__ x,
                                             const f16* __restrict__ Wh,
                                             const float* __restrict__ bq,
                                             const float* __restrict__ bk,
                                             const float* __restrict__ bv,
                                             f16* __restrict__ Qh,
                                             f16* __restrict__ Kh,
                                             f16* __restrict__ Vh) {
  __shared__ __align__(16) f16 xt[64 * 256];   // 32 KiB
  const int b = blockIdx.y, n0 = blockIdx.x * 64;
  const int tid = threadIdx.x;
  const int w = tid >> 6, lane = tid & 63;
  const int quad = lane >> 4, li = lane & 15;
  const int gt = w & 3, role = w >> 2;

  // ---- stage x tile (fp32 -> f16, swizzled) ----
  {
    const float* xb = x + (size_t)b * C_DIM * N_DIM + n0;
#pragma unroll
    for (int cg = 0; cg < 4; cg++) {
      f16x8 v;
#pragma unroll
      for (int j = 0; j < 8; j++) {
        int c = w * 32 + cg * 8 + j;
        v[j] = (f16)xb[(size_t)c * N_DIM + lane];
      }
      int chunk = w * 4 + cg;
      int slot = chunk ^ (lane & 7);
      *(f16x8*)(&xt[lane * 256 + slot * 8]) = v;
    }
  }
  __syncthreads();

  // ---- x fragments (shared by A- and B-roles) ----
  int xsl[8];
#pragma unroll
  for (int kf = 0; kf < 8; kf++) xsl[kf] = ((kf * 4 + quad) ^ (li & 7)) << 3;
  f16x8 xf[8];
  {
    const f16* xrow = xt + (gt * 16 + li) * 256;
#pragma unroll
    for (int kf = 0; kf < 8; kf++) xf[kf] = *(const f16x8*)(xrow + xsl[kf]);
  }

  // ---- Q or K: out[g][o], D rows = o ----
  {
    const f16* W = Wh + (size_t)role * 65536;
    const float* bias = role ? bk : bq;
    f16* out = role ? Kh : Qh;
    const size_t grow = (size_t)(b * N_DIM + n0 + gt * 16 + li) * C_DIM;
    for (int ot = 0; ot < 16; ot++) {
      f32x4 acc = {0.f, 0.f, 0.f, 0.f};
      const f16* wrow = W + (size_t)(ot * 16 + li) * C_DIM + quad * 8;
#pragma unroll
      for (int kf = 0; kf < 8; kf++) {
        f16x8 wf = *(const f16x8*)(wrow + kf * 32);
        acc = __builtin_amdgcn_mfma_f32_16x16x32_f16(wf, xf[kf], acc, 0, 0, 0);
      }
      const int o0 = ot * 16 + quad * 4;
      f16x4 st = {(f16)(acc[0] + bias[o0]), (f16)(acc[1] + bias[o0 + 1]),
                  (f16)(acc[2] + bias[o0 + 2]), (f16)(acc[3] + bias[o0 + 3])};
      *(f16x4*)(out + grow + o0) = st;
    }
  }

  // ---- V half: out[o][j], D rows = j ----
  {
    const f16* W = Wh + (size_t)2 * 65536;
#pragma unroll
    for (int ot8 = 0; ot8 < 8; ot8++) {
      const int ot = role * 8 + ot8;
      f32x4 acc = {0.f, 0.f, 0.f, 0.f};
      const f16* wrow = W + (size_t)(ot * 16 + li) * C_DIM + quad * 8;
#pragma unroll
      for (int kf = 0; kf < 8; kf++) {
        f16x8 wf = *(const f16x8*)(wrow + kf * 32);
        acc = __builtin_amdgcn_mfma_f32_16x16x32_f16(xf[kf], wf, acc, 0, 0, 0);
      }
      const float bb = bv[ot * 16 + li];
      f16x4 st = {(f16)(acc[0] + bb), (f16)(acc[1] + bb),
                  (f16)(acc[2] + bb), (f16)(acc[3] + bb)};
      *(f16x4*)(Vh + (size_t)(b * C_DIM + ot * 16 + li) * N_DIM +
                n0 + gt * 16 + quad * 4) = st;
    }
  }
}

// ---------------- fused attention (R6 structure + T13 defer-max + shfl-hoist) ----------------
// grid (64,4): 64-query block, batch. 8 waves: wq=w&3 (16 query cols each),
// wj=w>>2 (j-half of each 64-key tile). Pair (w, w+4) merges at the end.
// JT=64 keys/tile, NT=64 tiles. DMA staging (global_load_lds, 16B), dbuf.
// LDS layouts (f16 units), linear rows + XOR chunk swizzle (chunk = 8 f16 = 16B):
//   K: [64 rows][256], row r: 16B slot s holds global chunk s^(r&7).
//   V: [256 rows][64], row c: slot s holds chunk s^(c&7).
//   P (per wave): [16 i][32 j], row stride 40 f16 (80B, conflict-free).
// Merge scratch (after loop, reuses K/V region as f32):
//   per upper wave u: 16 cols x 260 f32; m/l at f32 offset 16640.
#define JT 64
#define NT (N_DIM / JT)
#define K0_OFF 0
#define K1_OFF 16384
#define V0_OFF 32768
#define V1_OFF 49152
#define P_OFF  65536
#define PSTR 40
#define SMEM_F16 70656        // 141312 B
#define MRG_WSTR 4160         // f32 per upper wave (16 cols * 260)
#define MRG_CSTR 260          // f32 col stride
#define ML_OFF   16640        // 4*4160
#define RESCALE_THR 8.0f      // defer-max threshold (P <= e^8 ~ 2981, f16-safe)

__global__ __launch_bounds__(512, 1) void k_attn(const f16* __restrict__ Qh,
                                                 const f16* __restrict__ Kh,
                                                 const f16* __restrict__ Vh,
                                                 const float* __restrict__ x,
                                                 const float* __restrict__ gamma_p,
                                                 float* __restrict__ out) {
  __shared__ __align__(16) f16 smem[SMEM_F16];
  const int b = blockIdx.y;
  const int tid = threadIdx.x;
  const int w = tid >> 6, lane = tid & 63;
  const int wq = w & 3, wj = w >> 2;
  const int quad = lane >> 4, li = lane & 15;
  const int lw = li & 7;
  const int ibase = blockIdx.x * 64 + wq * 16;

  // loop-invariant swizzled slot offsets (f16 units), static-indexed
  int ksl[8];
#pragma unroll
  for (int kf = 0; kf < 8; kf++) ksl[kf] = ((kf * 4 + quad) ^ lw) << 3;
  const int vsl = ((wj * 4 + quad) ^ lw) << 3;   // V j-chunk for this wave's half

  // Q fragments (B-operand: n = query col, k = channel)
  f16x8 qf[8];
  {
    const f16* qrow = Qh + (size_t)(b * N_DIM + ibase + li) * C_DIM + quad * 8;
#pragma unroll
    for (int kf = 0; kf < 8; kf++) qf[kf] = *(const f16x8*)(qrow + kf * 32);
  }
  const f16* Kb = Kh + (size_t)b * N_DIM * C_DIM;
  const f16* Vb = Vh + (size_t)b * C_DIM * N_DIM;
  f16* Pw = smem + P_OFF + w * 16 * PSTR;

  const float LOG2E = 1.4426950408889634f;
  float m = -3.0e38f, l = 0.0f;
  f32x4 acc[16];
#pragma unroll
  for (int ct = 0; ct < 16; ct++) acc[ct] = (f32x4){0.f, 0.f, 0.f, 0.f};

  // prologue: DMA tile 0 -> buf0 (pre-swizzled global source chunks)
  {
#pragma unroll
    for (int it = 0; it < 4; it++) {
      int p = w * 4 + it;
      int krsw = (2 * it + (lane >> 5)) & 7;     // (2p+(l>>5))&7, since 8w==0 mod 8
      dma16(Kb + (size_t)(2 * p + (lane >> 5)) * C_DIM + (((lane & 31) ^ krsw) * 8),
            smem + K0_OFF + p * 512);
      dma16(Vb + (size_t)(p * 8 + (lane >> 3)) * N_DIM + (((lane & 7) ^ (lane >> 3)) * 8),
            smem + V0_OFF + p * 512);
    }
  }
  __syncthreads();

  for (int t = 0; t < NT; t++) {
    const f16* Kc = smem + ((t & 1) ? K1_OFF : K0_OFF);
    const f16* Vc = smem + ((t & 1) ? V1_OFF : V0_OFF);

    // issue DMA for tile t+1 into the other buffer (drained at the barrier)
    if (t + 1 < NT) {
      f16* Kn = smem + ((t & 1) ? K0_OFF : K1_OFF);
      f16* Vn = smem + ((t & 1) ? V0_OFF : V1_OFF);
      const int jt = (t + 1) * JT;
      const f16* kg = Kb + (size_t)jt * C_DIM;
      const f16* vg = Vb + jt;
#pragma unroll
      for (int it = 0; it < 4; it++) {
        int p = w * 4 + it;
        int krsw = (2 * it + (lane >> 5)) & 7;
        dma16(kg + (size_t)(2 * p + (lane >> 5)) * C_DIM + (((lane & 31) ^ krsw) * 8),
              Kn + p * 512);
        dma16(vg + (size_t)(p * 8 + (lane >> 3)) * N_DIM + (((lane & 7) ^ (lane >> 3)) * 8),
              Vn + p * 512);
      }
    }

    // ---- S^T for this wave's j-half: rows j = wj*32 + sub*16 + (quad*4+reg) ----
    f32x4 s[2];
#pragma unroll
    for (int sub = 0; sub < 2; sub++) {
      f32x4 ss = {0.f, 0.f, 0.f, 0.f};
      const f16* krow = Kc + (wj * 32 + sub * 16 + li) * 256;  // row&7 == li&7
#pragma unroll
      for (int kf = 0; kf < 8; kf++) {
        f16x8 kfr = *(const f16x8*)(krow + ksl[kf]);
        ss = __builtin_amdgcn_mfma_f32_16x16x32_f16(kfr, qf[kf], ss, 0, 0, 0);
      }
      s[sub] = ss;
    }

    // ---- online softmax (T13 defer-max; shfl reduce hoisted into branch) ----
    // Gate on per-lane partial max pm: colmax > m+THR iff some lane's pm
    // does (colmax = max of 4 lanes' pm; __any spans the wave; m is
    // column-uniform since it only updates from post-shfl tm below).
    float pm = fmaxf(fmaxf(fmaxf(s[0][0], s[0][1]), fmaxf(s[0][2], s[0][3])),
                     fmaxf(fmaxf(s[1][0], s[1][1]), fmaxf(s[1][2], s[1][3])));
    if (__any(pm - m > RESCALE_THR)) {   // wave-uniform; rare after first tiles
      float tm = fmaxf(pm, __shfl_xor(pm, 16));
      tm = fmaxf(tm, __shfl_xor(tm, 32));
      float nm = fmaxf(m, tm);
      float alpha = exp2f((m - nm) * LOG2E);
      m = nm;
      l *= alpha;
#pragma unroll
      for (int ct = 0; ct < 16; ct++) {
        acc[ct][0] *= alpha; acc[ct][1] *= alpha;
        acc[ct][2] *= alpha; acc[ct][3] *= alpha;
      }
    }
#pragma unroll
    for (int sub = 0; sub < 2; sub++) {
      float p0 = exp2f((s[sub][0] - m) * LOG2E);
      float p1 = exp2f((s[sub][1] - m) * LOG2E);
      float p2 = exp2f((s[sub][2] - m) * LOG2E);
      float p3 = exp2f((s[sub][3] - m) * LOG2E);
      l += (p0 + p1) + (p2 + p3);
      *(f16x4*)(Pw + li * PSTR + sub * 16 + quad * 4) =
          (f16x4){(f16)p0, (f16)p1, (f16)p2, (f16)p3};
    }

    // ---- PV (half): O^T[c][i] += V[c][j-half] P^T[j-half][i], k = 32 ----
    f16x8 pf = *(const f16x8*)(Pw + li * PSTR + quad * 8);
#pragma unroll
    for (int ct = 0; ct < 16; ct++) {
      const f16* vrow = Vc + (ct * 16 + li) * 64;
      f16x8 v = *(const f16x8*)(vrow + vsl);
      acc[ct] = __builtin_amdgcn_mfma_f32_16x16x32_f16(v, pf, acc[ct], 0, 0, 0);
    }

    __syncthreads();   // waits readers of current bufs AND drains next-tile DMA
  }

  // ---- reduce l across quads; merge j-half partials via LDS (K/V region reused) ----
  l += __shfl_xor(l, 16);
  l += __shfl_xor(l, 32);

  float* mrg = (float*)smem;
  if (wj == 1) {
    const int u = wq;
    float* base = mrg + u * MRG_WSTR + li * MRG_CSTR;
#pragma unroll
    for (int ct = 0; ct < 16; ct++)
      *(f32x4*)(base + ct * 16 + quad * 4) = acc[ct];
    if (lane < 16) {
      mrg[ML_OFF + u * 32 + li] = m;
      mrg[ML_OFF + u * 32 + 16 + li] = l;
    }
  }
  __syncthreads();
  if (wj == 0) {
    const int u = wq;
    const float m_b = mrg[ML_OFF + u * 32 + li];
    const float l_b = mrg[ML_OFF + u * 32 + 16 + li];
    const float M = fmaxf(m, m_b);
    const float aa = exp2f((m - M) * LOG2E);
    const float ab = exp2f((m_b - M) * LOG2E);
    const float lm = aa * l + ab * l_b;
    const float scale = gamma_p[0] / lm;
    const float* base = mrg + u * MRG_WSTR + li * MRG_CSTR;

    const float* xb = x + (size_t)b * C_DIM * N_DIM;
    float* ob = out + (size_t)b * C_DIM * N_DIM;
    const int icol = ibase + li;
#pragma unroll
    for (int ct = 0; ct < 16; ct++) {
      f32x4 accb = *(const f32x4*)(base + ct * 16 + quad * 4);
#pragma unroll
      for (int r = 0; r < 4; r++) {
        size_t off = (size_t)(ct * 16 + quad * 4 + r) * N_DIM + icol;
        ob[off] = (acc[ct][r] * aa + accb[r] * ab) * scale + xb[off];
      }
    }
  }
}

extern "C" void kernel_launch(void* const* d_in, const int* in_sizes, int n_in,
                              void* d_out, int out_size, void* d_ws, size_t ws_size,
                              hipStream_t stream) {
  const float* x     = (const float*)d_in[0];
  const float* Wq    = (const float*)d_in[1];
  const float* bq    = (const float*)d_in[2];
  const float* Wk    = (const float*)d_in[3];
  const float* bk    = (const float*)d_in[4];
  const float* Wv    = (const float*)d_in[5];
  const float* bv    = (const float*)d_in[6];
  const float* gamma = (const float*)d_in[7];
  float* out = (float*)d_out;

  // workspace: Qh 8MB | Kh 8MB | Vh 8MB | Wh 384KB  (~24.4 MB)
  char* ws = (char*)d_ws;
  f16* Qh = (f16*)(ws);
  f16* Kh = (f16*)(ws + (size_t)8  * 1024 * 1024);
  f16* Vh = (f16*)(ws + (size_t)16 * 1024 * 1024);
  f16* Wh = (f16*)(ws + (size_t)24 * 1024 * 1024);

  k_cast_w<<<dim3(768), 256, 0, stream>>>(Wq, Wk, Wv, Wh);
  k_qkv<<<dim3(64, 4), 512, 0, stream>>>(x, Wh, bq, bk, bv, Qh, Kh, Vh);
  k_attn<<<dim3(64, 4), 512, 0, stream>>>(Qh, Kh, Vh, x, gamma, out);
}

// Round 18
// 241.078 us; speedup vs baseline: 1.7812x; 1.0004x over previous
//
#include <hip/hip_runtime.h>
#include <hip/hip_bf16.h>
#include <cstdint>

// SpatialAttentionModule: x[4,256,64,64] fp32; q=Wq x, k=Wk x, v=Wv x (1x1 conv);
// energy = q^T k per batch (N=4096), softmax over j, out = gamma*(v@attn^T) + x.
//
// Round-18: T5 s_setprio on the R17 base (241.2us, k_attn 132.0us; T13 +
// shfl-hoist banked, both at predicted magnitude). Single change: wrap the
// S^T and PV MFMA clusters in s_setprio(1)/(0). Mechanism: 8 waves are
// barrier-synced once per tile but drift across the S->softmax->PV phase
// (LDS contention differs per wj/wq), so the CU scheduler can favor
// MFMA-issuing waves over load/VALU waves (guide T5: +4-7% attn m191; null
// on lockstep GEMM m190 - ours has more drift than GEMM, less than 1-wave
// attn). Zero correctness risk. Decision rule: <1us -> declare plateau.
// Kernel remains latency-bound: LDS ~54%, VALU ~34%, MFMA ~22%, 2 waves/SIMD
// grid-capped, all structural alternatives measured worse.
// k_cast_w / k_qkv byte-identical to R8.
// MFMA layouts (HW-verified, learn_hip m89/m91, dtype-independent):
//   A[m=lane&15][k=quad*8+j], B[k=quad*8+j][n=lane&15], C/D: col=lane&15, row=quad*4+reg.

#define C_DIM 256
#define N_DIM 4096
#define B_DIM 4

typedef _Float16 f16;
typedef f16 f16x8 __attribute__((ext_vector_type(8)));
typedef f16 f16x4 __attribute__((ext_vector_type(4)));
typedef float f32x4 __attribute__((ext_vector_type(4)));

__device__ __forceinline__ void dma16(const f16* g, f16* l) {
  __builtin_amdgcn_global_load_lds(
      (const __attribute__((address_space(1))) unsigned int*)g,
      (__attribute__((address_space(3))) unsigned int*)l, 16, 0, 0);
}

// ---------------- prep: cast 3 weight matrices -> fp16 [3*256][256] ----------------
__global__ __launch_bounds__(256) void k_cast_w(const float* __restrict__ Wq,
                                                const float* __restrict__ Wk,
                                                const float* __restrict__ Wv,
                                                f16* __restrict__ Wh) {
  int i = blockIdx.x * 256 + threadIdx.x;          // 0 .. 3*65536-1
  int sel = i >> 16, j = i & 65535;
  const float* s = (sel == 0) ? Wq : (sel == 1) ? Wk : Wv;
  Wh[i] = (f16)s[j];
}

// ---------------- fused QKV projection (byte-identical to R8) ----------------
__global__ __launch_bounds__(512) void k_qkv(const float* __restrict__ x,
                                             const f16* __restrict__ Wh,
                                             const float* __restrict__ bq,
                                             const float* __restrict__ bk,
                                             const float* __restrict__ bv,
                                             f16* __restrict__ Qh,
                                             f16* __restrict__ Kh,
                                             f16* __restrict__ Vh) {
  __shared__ __align__(16) f16 xt[64 * 256];   // 32 KiB
  const int b = blockIdx.y, n0 = blockIdx.x * 64;
  const int tid = threadIdx.x;
  const int w = tid >> 6, lane = tid & 63;
  const int quad = lane >> 4, li = lane & 15;
  const int gt = w & 3, role = w >> 2;

  // ---- stage x tile (fp32 -> f16, swizzled) ----
  {
    const float* xb = x + (size_t)b * C_DIM * N_DIM + n0;
#pragma unroll
    for (int cg = 0; cg < 4; cg++) {
      f16x8 v;
#pragma unroll
      for (int j = 0; j < 8; j++) {
        int c = w * 32 + cg * 8 + j;
        v[j] = (f16)xb[(size_t)c * N_DIM + lane];
      }
      int chunk = w * 4 + cg;
      int slot = chunk ^ (lane & 7);
      *(f16x8*)(&xt[lane * 256 + slot * 8]) = v;
    }
  }
  __syncthreads();

  // ---- x fragments (shared by A- and B-roles) ----
  int xsl[8];
#pragma unroll
  for (int kf = 0; kf < 8; kf++) xsl[kf] = ((kf * 4 + quad) ^ (li & 7)) << 3;
  f16x8 xf[8];
  {
    const f16* xrow = xt + (gt * 16 + li) * 256;
#pragma unroll
    for (int kf = 0; kf < 8; kf++) xf[kf] = *(const f16x8*)(xrow + xsl[kf]);
  }

  // ---- Q or K: out[g][o], D rows = o ----
  {
    const f16* W = Wh + (size_t)role * 65536;
    const float* bias = role ? bk : bq;
    f16* out = role ? Kh : Qh;
    const size_t grow = (size_t)(b * N_DIM + n0 + gt * 16 + li) * C_DIM;
    for (int ot = 0; ot < 16; ot++) {
      f32x4 acc = {0.f, 0.f, 0.f, 0.f};
      const f16* wrow = W + (size_t)(ot * 16 + li) * C_DIM + quad * 8;
#pragma unroll
      for (int kf = 0; kf < 8; kf++) {
        f16x8 wf = *(const f16x8*)(wrow + kf * 32);
        acc = __builtin_amdgcn_mfma_f32_16x16x32_f16(wf, xf[kf], acc, 0, 0, 0);
      }
      const int o0 = ot * 16 + quad * 4;
      f16x4 st = {(f16)(acc[0] + bias[o0]), (f16)(acc[1] + bias[o0 + 1]),
                  (f16)(acc[2] + bias[o0 + 2]), (f16)(acc[3] + bias[o0 + 3])};
      *(f16x4*)(out + grow + o0) = st;
    }
  }

  // ---- V half: out[o][j], D rows = j ----
  {
    const f16* W = Wh + (size_t)2 * 65536;
#pragma unroll
    for (int ot8 = 0; ot8 < 8; ot8++) {
      const int ot = role * 8 + ot8;
      f32x4 acc = {0.f, 0.f, 0.f, 0.f};
      const f16* wrow = W + (size_t)(ot * 16 + li) * C_DIM + quad * 8;
#pragma unroll
      for (int kf = 0; kf < 8; kf++) {
        f16x8 wf = *(const f16x8*)(wrow + kf * 32);
        acc = __builtin_amdgcn_mfma_f32_16x16x32_f16(xf[kf], wf, acc, 0, 0, 0);
      }
      const float bb = bv[ot * 16 + li];
      f16x4 st = {(f16)(acc[0] + bb), (f16)(acc[1] + bb),
                  (f16)(acc[2] + bb), (f16)(acc[3] + bb)};
      *(f16x4*)(Vh + (size_t)(b * C_DIM + ot * 16 + li) * N_DIM +
                n0 + gt * 16 + quad * 4) = st;
    }
  }
}

// ---------------- fused attention (R6 + T13 + shfl-hoist + T5 setprio) ----------------
// grid (64,4): 64-query block, batch. 8 waves: wq=w&3 (16 query cols each),
// wj=w>>2 (j-half of each 64-key tile). Pair (w, w+4) merges at the end.
// JT=64 keys/tile, NT=64 tiles. DMA staging (global_load_lds, 16B), dbuf.
// LDS layouts (f16 units), linear rows + XOR chunk swizzle (chunk = 8 f16 = 16B):
//   K: [64 rows][256], row r: 16B slot s holds global chunk s^(r&7).
//   V: [256 rows][64], row c: slot s holds chunk s^(c&7).
//   P (per wave): [16 i][32 j], row stride 40 f16 (80B, conflict-free).
// Merge scratch (after loop, reuses K/V region as f32):
//   per upper wave u: 16 cols x 260 f32; m/l at f32 offset 16640.
#define JT 64
#define NT (N_DIM / JT)
#define K0_OFF 0
#define K1_OFF 16384
#define V0_OFF 32768
#define V1_OFF 49152
#define P_OFF  65536
#define PSTR 40
#define SMEM_F16 70656        // 141312 B
#define MRG_WSTR 4160         // f32 per upper wave (16 cols * 260)
#define MRG_CSTR 260          // f32 col stride
#define ML_OFF   16640        // 4*4160
#define RESCALE_THR 8.0f      // defer-max threshold (P <= e^8 ~ 2981, f16-safe)

__global__ __launch_bounds__(512, 1) void k_attn(const f16* __restrict__ Qh,
                                                 const f16* __restrict__ Kh,
                                                 const f16* __restrict__ Vh,
                                                 const float* __restrict__ x,
                                                 const float* __restrict__ gamma_p,
                                                 float* __restrict__ out) {
  __shared__ __align__(16) f16 smem[SMEM_F16];
  const int b = blockIdx.y;
  const int tid = threadIdx.x;
  const int w = tid >> 6, lane = tid & 63;
  const int wq = w & 3, wj = w >> 2;
  const int quad = lane >> 4, li = lane & 15;
  const int lw = li & 7;
  const int ibase = blockIdx.x * 64 + wq * 16;

  // loop-invariant swizzled slot offsets (f16 units), static-indexed
  int ksl[8];
#pragma unroll
  for (int kf = 0; kf < 8; kf++) ksl[kf] = ((kf * 4 + quad) ^ lw) << 3;
  const int vsl = ((wj * 4 + quad) ^ lw) << 3;   // V j-chunk for this wave's half

  // Q fragments (B-operand: n = query col, k = channel)
  f16x8 qf[8];
  {
    const f16* qrow = Qh + (size_t)(b * N_DIM + ibase + li) * C_DIM + quad * 8;
#pragma unroll
    for (int kf = 0; kf < 8; kf++) qf[kf] = *(const f16x8*)(qrow + kf * 32);
  }
  const f16* Kb = Kh + (size_t)b * N_DIM * C_DIM;
  const f16* Vb = Vh + (size_t)b * C_DIM * N_DIM;
  f16* Pw = smem + P_OFF + w * 16 * PSTR;

  const float LOG2E = 1.4426950408889634f;
  float m = -3.0e38f, l = 0.0f;
  f32x4 acc[16];
#pragma unroll
  for (int ct = 0; ct < 16; ct++) acc[ct] = (f32x4){0.f, 0.f, 0.f, 0.f};

  // prologue: DMA tile 0 -> buf0 (pre-swizzled global source chunks)
  {
#pragma unroll
    for (int it = 0; it < 4; it++) {
      int p = w * 4 + it;
      int krsw = (2 * it + (lane >> 5)) & 7;     // (2p+(l>>5))&7, since 8w==0 mod 8
      dma16(Kb + (size_t)(2 * p + (lane >> 5)) * C_DIM + (((lane & 31) ^ krsw) * 8),
            smem + K0_OFF + p * 512);
      dma16(Vb + (size_t)(p * 8 + (lane >> 3)) * N_DIM + (((lane & 7) ^ (lane >> 3)) * 8),
            smem + V0_OFF + p * 512);
    }
  }
  __syncthreads();

  for (int t = 0; t < NT; t++) {
    const f16* Kc = smem + ((t & 1) ? K1_OFF : K0_OFF);
    const f16* Vc = smem + ((t & 1) ? V1_OFF : V0_OFF);

    // issue DMA for tile t+1 into the other buffer (drained at the barrier)
    if (t + 1 < NT) {
      f16* Kn = smem + ((t & 1) ? K0_OFF : K1_OFF);
      f16* Vn = smem + ((t & 1) ? V0_OFF : V1_OFF);
      const int jt = (t + 1) * JT;
      const f16* kg = Kb + (size_t)jt * C_DIM;
      const f16* vg = Vb + jt;
#pragma unroll
      for (int it = 0; it < 4; it++) {
        int p = w * 4 + it;
        int krsw = (2 * it + (lane >> 5)) & 7;
        dma16(kg + (size_t)(2 * p + (lane >> 5)) * C_DIM + (((lane & 31) ^ krsw) * 8),
              Kn + p * 512);
        dma16(vg + (size_t)(p * 8 + (lane >> 3)) * N_DIM + (((lane & 7) ^ (lane >> 3)) * 8),
              Vn + p * 512);
      }
    }

    // ---- S^T for this wave's j-half: rows j = wj*32 + sub*16 + (quad*4+reg) ----
    f32x4 s[2];
    __builtin_amdgcn_s_setprio(1);
#pragma unroll
    for (int sub = 0; sub < 2; sub++) {
      f32x4 ss = {0.f, 0.f, 0.f, 0.f};
      const f16* krow = Kc + (wj * 32 + sub * 16 + li) * 256;  // row&7 == li&7
#pragma unroll
      for (int kf = 0; kf < 8; kf++) {
        f16x8 kfr = *(const f16x8*)(krow + ksl[kf]);
        ss = __builtin_amdgcn_mfma_f32_16x16x32_f16(kfr, qf[kf], ss, 0, 0, 0);
      }
      s[sub] = ss;
    }
    __builtin_amdgcn_s_setprio(0);

    // ---- online softmax (T13 defer-max; shfl reduce hoisted into branch) ----
    // Gate on per-lane partial max pm: colmax > m+THR iff some lane's pm
    // does (colmax = max of 4 lanes' pm; __any spans the wave; m is
    // column-uniform since it only updates from post-shfl tm below).
    float pm = fmaxf(fmaxf(fmaxf(s[0][0], s[0][1]), fmaxf(s[0][2], s[0][3])),
                     fmaxf(fmaxf(s[1][0], s[1][1]), fmaxf(s[1][2], s[1][3])));
    if (__any(pm - m > RESCALE_THR)) {   // wave-uniform; rare after first tiles
      float tm = fmaxf(pm, __shfl_xor(pm, 16));
      tm = fmaxf(tm, __shfl_xor(tm, 32));
      float nm = fmaxf(m, tm);
      float alpha = exp2f((m - nm) * LOG2E);
      m = nm;
      l *= alpha;
#pragma unroll
      for (int ct = 0; ct < 16; ct++) {
        acc[ct][0] *= alpha; acc[ct][1] *= alpha;
        acc[ct][2] *= alpha; acc[ct][3] *= alpha;
      }
    }
#pragma unroll
    for (int sub = 0; sub < 2; sub++) {
      float p0 = exp2f((s[sub][0] - m) * LOG2E);
      float p1 = exp2f((s[sub][1] - m) * LOG2E);
      float p2 = exp2f((s[sub][2] - m) * LOG2E);
      float p3 = exp2f((s[sub][3] - m) * LOG2E);
      l += (p0 + p1) + (p2 + p3);
      *(f16x4*)(Pw + li * PSTR + sub * 16 + quad * 4) =
          (f16x4){(f16)p0, (f16)p1, (f16)p2, (f16)p3};
    }

    // ---- PV (half): O^T[c][i] += V[c][j-half] P^T[j-half][i], k = 32 ----
    f16x8 pf = *(const f16x8*)(Pw + li * PSTR + quad * 8);
    __builtin_amdgcn_s_setprio(1);
#pragma unroll
    for (int ct = 0; ct < 16; ct++) {
      const f16* vrow = Vc + (ct * 16 + li) * 64;
      f16x8 v = *(const f16x8*)(vrow + vsl);
      acc[ct] = __builtin_amdgcn_mfma_f32_16x16x32_f16(v, pf, acc[ct], 0, 0, 0);
    }
    __builtin_amdgcn_s_setprio(0);

    __syncthreads();   // waits readers of current bufs AND drains next-tile DMA
  }

  // ---- reduce l across quads; merge j-half partials via LDS (K/V region reused) ----
  l += __shfl_xor(l, 16);
  l += __shfl_xor(l, 32);

  float* mrg = (float*)smem;
  if (wj == 1) {
    const int u = wq;
    float* base = mrg + u * MRG_WSTR + li * MRG_CSTR;
#pragma unroll
    for (int ct = 0; ct < 16; ct++)
      *(f32x4*)(base + ct * 16 + quad * 4) = acc[ct];
    if (lane < 16) {
      mrg[ML_OFF + u * 32 + li] = m;
      mrg[ML_OFF + u * 32 + 16 + li] = l;
    }
  }
  __syncthreads();
  if (wj == 0) {
    const int u = wq;
    const float m_b = mrg[ML_OFF + u * 32 + li];
    const float l_b = mrg[ML_OFF + u * 32 + 16 + li];
    const float M = fmaxf(m, m_b);
    const float aa = exp2f((m - M) * LOG2E);
    const float ab = exp2f((m_b - M) * LOG2E);
    const float lm = aa * l + ab * l_b;
    const float scale = gamma_p[0] / lm;
    const float* base = mrg + u * MRG_WSTR + li * MRG_CSTR;

    const float* xb = x + (size_t)b * C_DIM * N_DIM;
    float* ob = out + (size_t)b * C_DIM * N_DIM;
    const int icol = ibase + li;
#pragma unroll
    for (int ct = 0; ct < 16; ct++) {
      f32x4 accb = *(const f32x4*)(base + ct * 16 + quad * 4);
#pragma unroll
      for (int r = 0; r < 4; r++) {
        size_t off = (size_t)(ct * 16 + quad * 4 + r) * N_DIM + icol;
        ob[off] = (acc[ct][r] * aa + accb[r] * ab) * scale + xb[off];
      }
    }
  }
}

extern "C" void kernel_launch(void* const* d_in, const int* in_sizes, int n_in,
                              void* d_out, int out_size, void* d_ws, size_t ws_size,
                              hipStream_t stream) {
  const float* x     = (const float*)d_in[0];
  const float* Wq    = (const float*)d_in[1];
  const float* bq    = (const float*)d_in[2];
  const float* Wk    = (const float*)d_in[3];
  const float* bk    = (const float*)d_in[4];
  const float* Wv    = (const float*)d_in[5];
  const float* bv    = (const float*)d_in[6];
  const float* gamma = (const float*)d_in[7];
  float* out = (float*)d_out;

  // workspace: Qh 8MB | Kh 8MB | Vh 8MB | Wh 384KB  (~24.4 MB)
  char* ws = (char*)d_ws;
  f16* Qh = (f16*)(ws);
  f16* Kh = (f16*)(ws + (size_t)8  * 1024 * 1024);
  f16* Vh = (f16*)(ws + (size_t)16 * 1024 * 1024);
  f16* Wh = (f16*)(ws + (size_t)24 * 1024 * 1024);

  k_cast_w<<<dim3(768), 256, 0, stream>>>(Wq, Wk, Wv, Wh);
  k_qkv<<<dim3(64, 4), 512, 0, stream>>>(x, Wh, bq, bk, bv, Qh, Kh, Vh);
  k_attn<<<dim3(64, 4), 512, 0, stream>>>(Qh, Kh, Vh, x, gamma, out);
}